// Round 1
// baseline (4633.769 us; speedup 1.0000x reference)
//
#include <hip/hip_runtime.h>

#define NN 100000
#define IND 64
#define HID 128
#define NE 1600000

// ---------------- zero helper ----------------
__global__ __launch_bounds__(256) void zero4_kernel(float4* __restrict__ p, int n4) {
    int i = blockIdx.x * 256 + threadIdx.x;
    if (i < n4) p[i] = make_float4(0.f, 0.f, 0.f, 0.f);
}

// ---------------- scatter layer 1: agg[dst] += x[src], cnt[dst] += 1 ----------------
// 16 threads per edge, each handles 4 of 64 dims (float4 read, 4 atomics)
__global__ __launch_bounds__(256) void scatter1_kernel(
    const float* __restrict__ x, const int* __restrict__ src,
    const int* __restrict__ dst, float* __restrict__ agg,
    float* __restrict__ cnt) {
    unsigned tid = blockIdx.x * 256u + threadIdx.x;
    unsigned e  = tid >> 4;
    unsigned ch = tid & 15u;
    if (e >= NE) return;
    int s = src[e], d = dst[e];
    float4 v = *reinterpret_cast<const float4*>(x + (size_t)s * IND + ch * 4u);
    float* a = agg + (size_t)d * IND + ch * 4u;
    unsafeAtomicAdd(a + 0, v.x);
    unsafeAtomicAdd(a + 1, v.y);
    unsafeAtomicAdd(a + 2, v.z);
    unsafeAtomicAdd(a + 3, v.w);
    if (ch == 0) unsafeAtomicAdd(cnt + d, 1.0f);
}

// ---------------- scatter layer 2: agg[dst] += h1[src] (128 dims) ----------------
__global__ __launch_bounds__(256) void scatter2_kernel(
    const float* __restrict__ h1, const int* __restrict__ src,
    const int* __restrict__ dst, float* __restrict__ agg) {
    unsigned tid = blockIdx.x * 256u + threadIdx.x;
    unsigned e  = tid >> 5;
    unsigned ch = tid & 31u;
    if (e >= NE) return;
    int s = src[e], d = dst[e];
    float4 v = *reinterpret_cast<const float4*>(h1 + (size_t)s * HID + ch * 4u);
    float* a = agg + (size_t)d * HID + ch * 4u;
    unsafeAtomicAdd(a + 0, v.x);
    unsafeAtomicAdd(a + 1, v.y);
    unsafeAtomicAdd(a + 2, v.z);
    unsafeAtomicAdd(a + 3, v.w);
}

// ---------------- layer 1: h1 = relu(mean1 @ Wl + x @ Wr + b) ----------------
// one block (128 threads) per node; thread j computes output dim j
__global__ __launch_bounds__(128) void layer1_kernel(
    const float* __restrict__ x, const float* __restrict__ agg1,
    const float* __restrict__ cnt, const float* __restrict__ Wl,
    const float* __restrict__ Wr, const float* __restrict__ b,
    float* __restrict__ h1) {
    int i = blockIdx.x;
    int j = threadIdx.x;
    __shared__ float sm[IND * 2];  // [0..63]=x row, [64..127]=mean row
    float c  = cnt[i];
    float ic = 1.0f / fmaxf(c, 1.0f);
    if (j < IND) {
        sm[j] = x[(size_t)i * IND + j];
    } else {
        int k = j - IND;
        sm[IND + k] = agg1[(size_t)i * IND + k] * ic;
    }
    __syncthreads();
    float acc = b[j];
    #pragma unroll
    for (int k = 0; k < IND; ++k) {
        acc += sm[IND + k] * Wl[k * HID + j] + sm[k] * Wr[k * HID + j];
    }
    h1[(size_t)i * HID + j] = fmaxf(acc, 0.0f);
}

// ---------------- layer 2 (+ fused output head) ----------------
// h2 = mean2 @ Wl2 + h1 @ Wr2 + b2 ; out = h2 @ Wout + bout
// agg2 is read from the h2 region and overwritten in place (staged via LDS).
__global__ __launch_bounds__(128) void layer2_kernel(
    const float* __restrict__ h1, float* __restrict__ h2 /* holds agg2 */,
    const float* __restrict__ cnt, const float* __restrict__ Wl,
    const float* __restrict__ Wr, const float* __restrict__ b,
    const float* __restrict__ Wout, const float* __restrict__ bout,
    float* __restrict__ out) {
    int i = blockIdx.x;
    int j = threadIdx.x;
    __shared__ float sm[HID * 2];  // [0..127]=h1 row, [128..255]=mean2 row
    __shared__ float red[HID];
    float c  = cnt[i];
    float ic = 1.0f / fmaxf(c, 1.0f);
    sm[j]       = h1[(size_t)i * HID + j];
    sm[HID + j] = h2[(size_t)i * HID + j] * ic;   // agg2 -> mean2
    __syncthreads();
    float acc = b[j];
    #pragma unroll
    for (int k = 0; k < HID; ++k) {
        acc += sm[HID + k] * Wl[k * HID + j] + sm[k] * Wr[k * HID + j];
    }
    h2[(size_t)i * HID + j] = acc;   // safe: all reads staged before barrier
    red[j] = acc * Wout[j];
    __syncthreads();
    if (j < 64) {
        float v = red[j] + red[j + 64];
        #pragma unroll
        for (int off = 32; off > 0; off >>= 1) v += __shfl_down(v, off);
        if (j == 0) out[i] = v + bout[0];
    }
}

extern "C" void kernel_launch(void* const* d_in, const int* in_sizes, int n_in,
                              void* d_out, int out_size, void* d_ws, size_t ws_size,
                              hipStream_t stream) {
    const float* x    = (const float*)d_in[0];
    const int*   eidx = (const int*)d_in[1];
    const int*   src  = eidx;            // edge_index[0]
    const int*   dst  = eidx + NE;       // edge_index[1]
    const float* Wl1  = (const float*)d_in[2];
    const float* Wr1  = (const float*)d_in[3];
    const float* b1   = (const float*)d_in[4];
    const float* Wl2  = (const float*)d_in[5];
    const float* Wr2  = (const float*)d_in[6];
    const float* b2   = (const float*)d_in[7];
    const float* Wout = (const float*)d_in[8];
    const float* bout = (const float*)d_in[9];

    float* out = (float*)d_out;                    // [NN]
    float* h1  = out + NN;                         // [NN, HID]
    float* h2  = h1 + (size_t)NN * HID;            // [NN, HID] (also agg scratch)
    float* cnt = (float*)d_ws;                     // [NN]

    // 1) zero cnt and agg1 (agg1 lives compactly [NN,64] in the h2 region)
    zero4_kernel<<<(NN / 4 + 255) / 256, 256, 0, stream>>>((float4*)cnt, NN / 4);
    zero4_kernel<<<((NN * IND / 4) + 255) / 256, 256, 0, stream>>>((float4*)h2, NN * IND / 4);

    // 2) scatter layer 1
    scatter1_kernel<<<(NE * 16) / 256, 256, 0, stream>>>(x, src, dst, h2, cnt);

    // 3) layer 1 dense
    layer1_kernel<<<NN, 128, 0, stream>>>(x, h2, cnt, Wl1, Wr1, b1, h1);

    // 4) zero agg2 (full h2 region)
    zero4_kernel<<<((NN * HID / 4) + 255) / 256, 256, 0, stream>>>((float4*)h2, NN * HID / 4);

    // 5) scatter layer 2
    scatter2_kernel<<<(NE * 32) / 256, 256, 0, stream>>>(h1, src, dst, h2);

    // 6) layer 2 dense + fused output head
    layer2_kernel<<<NN, 128, 0, stream>>>(h1, h2, cnt, Wl2, Wr2, b2, Wout, bout, out);
}

// Round 2
// 1005.544 us; speedup vs baseline: 4.6082x; 4.6082x over previous
//
#include <hip/hip_runtime.h>

#define NN 100000
#define IND 64
#define HID 128
#define NE 1600000
#define SCAN_CHUNK 1024
#define NSB ((NN + SCAN_CHUNK - 1) / SCAN_CHUNK)   // 98 scan blocks

// ============================ CSR build ============================

__global__ __launch_bounds__(256) void zero_int_kernel(int4* __restrict__ p, int n4) {
    int i = blockIdx.x * 256 + threadIdx.x;
    if (i < n4) p[i] = make_int4(0, 0, 0, 0);
}

__global__ __launch_bounds__(256) void hist_kernel(const int* __restrict__ dst,
                                                   int* __restrict__ cnt) {
    int e = blockIdx.x * 256 + threadIdx.x;
    if (e < NE) atomicAdd(&cnt[dst[e]], 1);
}

// per-chunk sums
__global__ __launch_bounds__(256) void scanA_kernel(const int* __restrict__ cnt,
                                                    int* __restrict__ bsums) {
    int b = blockIdx.x, t = threadIdx.x;
    int base = b * SCAN_CHUNK + t * 4;
    int s = 0;
    #pragma unroll
    for (int k = 0; k < 4; ++k) { int i = base + k; if (i < NN) s += cnt[i]; }
    #pragma unroll
    for (int o = 32; o > 0; o >>= 1) s += __shfl_down(s, o);
    __shared__ int wsum[4];
    if ((t & 63) == 0) wsum[t >> 6] = s;
    __syncthreads();
    if (t == 0) bsums[b] = wsum[0] + wsum[1] + wsum[2] + wsum[3];
}

// exclusive scan of the 98 chunk sums (trivial size)
__global__ void scanB_kernel(int* __restrict__ bsums) {
    int acc = 0;
    for (int i = 0; i < NSB; ++i) { int v = bsums[i]; bsums[i] = acc; acc += v; }
}

// per-chunk exclusive scan -> off[], and cur[] = off[]
__global__ __launch_bounds__(256) void scanC_kernel(const int* __restrict__ cnt,
                                                    const int* __restrict__ bsums,
                                                    int* __restrict__ off,
                                                    int* __restrict__ cur) {
    int b = blockIdx.x, t = threadIdx.x;
    int lane = t & 63, w = t >> 6;
    int base = b * SCAN_CHUNK + t * 4;
    int v[4]; int s = 0;
    #pragma unroll
    for (int k = 0; k < 4; ++k) {
        int i = base + k;
        v[k] = (i < NN) ? cnt[i] : 0;
        s += v[k];
    }
    int inc = s;
    #pragma unroll
    for (int o = 1; o < 64; o <<= 1) {
        int xv = __shfl_up(inc, o);
        if (lane >= o) inc += xv;
    }
    __shared__ int wsum[4];
    if (lane == 63) wsum[w] = inc;
    __syncthreads();
    int wbase = 0;
    for (int i = 0; i < w; ++i) wbase += wsum[i];
    int ex = bsums[b] + wbase + (inc - s);
    #pragma unroll
    for (int k = 0; k < 4; ++k) {
        int i = base + k;
        if (i < NN) { off[i] = ex; cur[i] = ex; }
        ex += v[k];
    }
}

__global__ __launch_bounds__(256) void fill_kernel(const int* __restrict__ src,
                                                   const int* __restrict__ dst,
                                                   int* __restrict__ cur,
                                                   int* __restrict__ srcs) {
    int e = blockIdx.x * 256 + threadIdx.x;
    if (e < NE) {
        int p = atomicAdd(&cur[dst[e]], 1);
        srcs[p] = src[e];
    }
}

// ============================ gather means ============================

// one wave per node (64 dims); mean1 parked in h1 region cols [0,64)
__global__ __launch_bounds__(256) void agg1_kernel(const float* __restrict__ x,
                                                   const int* __restrict__ srcs,
                                                   const int* __restrict__ off,
                                                   const int* __restrict__ cnt,
                                                   float* __restrict__ mean1 /*h1 region*/) {
    int t = threadIdx.x;
    int n = blockIdx.x * 4 + (t >> 6);
    int d = t & 63;
    int s0 = off[n], deg = cnt[n];
    float acc = 0.f;
    for (int e = 0; e < deg; ++e) {
        int s = srcs[s0 + e];
        acc += x[(size_t)s * IND + d];
    }
    mean1[(size_t)n * HID + d] = acc / fmaxf((float)deg, 1.f);
}

// two waves per node (128 dims); mean2 parked in h2 region
__global__ __launch_bounds__(256) void agg2_kernel(const float* __restrict__ h1,
                                                   const int* __restrict__ srcs,
                                                   const int* __restrict__ off,
                                                   const int* __restrict__ cnt,
                                                   float* __restrict__ mean2 /*h2 region*/) {
    int t = threadIdx.x;
    int n = blockIdx.x * 2 + (t >> 7);
    int d = t & 127;
    int s0 = off[n], deg = cnt[n];
    float acc = 0.f;
    for (int e = 0; e < deg; ++e) {
        int s = srcs[s0 + e];
        acc += h1[(size_t)s * HID + d];
    }
    mean2[(size_t)n * HID + d] = acc / fmaxf((float)deg, 1.f);
}

// ============================ dense layers ============================

// 16 nodes/block, 256 threads; in = [x | mean1] (K=128); h1 = relu(in @ Wcat + b1)
// mean1 lives in the h1 rows we overwrite (staged to LDS before the barrier).
__global__ __launch_bounds__(256) void gemm1_kernel(const float* __restrict__ x,
                                                    const float* __restrict__ Wl,
                                                    const float* __restrict__ Wr,
                                                    const float* __restrict__ b,
                                                    float* __restrict__ h1) {
    __shared__ float in[16][128];
    int t = threadIdx.x;
    int node0 = blockIdx.x * 16;
    for (int idx = t; idx < 16 * 128; idx += 256) {
        int r = idx >> 7, c = idx & 127;
        in[r][c] = (c < IND) ? x[(size_t)(node0 + r) * IND + c]
                             : h1[(size_t)(node0 + r) * HID + (c - IND)];
    }
    __syncthreads();
    int j = t & 127, g = t >> 7;           // g in {0,1}: nodes g*8 .. g*8+7
    float acc[8];
    float bj = b[j];
    #pragma unroll
    for (int q = 0; q < 8; ++q) acc[q] = bj;
    for (int k = 0; k < 128; ++k) {
        float wv = (k < IND) ? Wr[k * HID + j] : Wl[(k - IND) * HID + j];
        #pragma unroll
        for (int q = 0; q < 8; ++q) acc[q] += in[g * 8 + q][k] * wv;
    }
    #pragma unroll
    for (int q = 0; q < 8; ++q)
        h1[(size_t)(node0 + g * 8 + q) * HID + j] = fmaxf(acc[q], 0.f);
}

// 16 nodes/block, 256 threads; in = [h1 | mean2] (K=256); h2 = in @ Wcat + b2
// + fused head: out = h2 @ Wout + bout. mean2 lives in the h2 rows we overwrite.
__global__ __launch_bounds__(256) void gemm2_kernel(const float* __restrict__ h1,
                                                    const float* __restrict__ Wl,
                                                    const float* __restrict__ Wr,
                                                    const float* __restrict__ b,
                                                    const float* __restrict__ Wout,
                                                    const float* __restrict__ bout,
                                                    float* __restrict__ h2,
                                                    float* __restrict__ out) {
    __shared__ float in[16][256];
    __shared__ float part[4][8];
    int t = threadIdx.x;
    int node0 = blockIdx.x * 16;
    for (int idx = t; idx < 16 * 256; idx += 256) {
        int r = idx >> 8, c = idx & 255;
        in[r][c] = (c < HID) ? h1[(size_t)(node0 + r) * HID + c]
                             : h2[(size_t)(node0 + r) * HID + (c - HID)];
    }
    __syncthreads();
    int j = t & 127, g = t >> 7, lane = t & 63, w = t >> 6;
    float acc[8];
    float bj = b[j];
    #pragma unroll
    for (int q = 0; q < 8; ++q) acc[q] = bj;
    for (int k = 0; k < 256; ++k) {
        float wv = (k < HID) ? Wr[k * HID + j] : Wl[(k - HID) * HID + j];
        #pragma unroll
        for (int q = 0; q < 8; ++q) acc[q] += in[g * 8 + q][k] * wv;
    }
    float wo = Wout[j];
    #pragma unroll
    for (int q = 0; q < 8; ++q)
        h2[(size_t)(node0 + g * 8 + q) * HID + j] = acc[q];
    // head: reduce acc[q]*Wout[j] over j (two waves per g-group)
    #pragma unroll
    for (int q = 0; q < 8; ++q) {
        float v = acc[q] * wo;
        #pragma unroll
        for (int o = 32; o > 0; o >>= 1) v += __shfl_down(v, o);
        if (lane == 0) part[w][q] = v;
    }
    __syncthreads();
    if (t < 16) {
        int gg = t >> 3, q = t & 7;
        out[node0 + t] = part[2 * gg][q] + part[2 * gg + 1][q] + bout[0];
    }
}

// ===================== fallback (atomic scatter path) =====================

__global__ __launch_bounds__(256) void zero4_kernel(float4* __restrict__ p, int n4) {
    int i = blockIdx.x * 256 + threadIdx.x;
    if (i < n4) p[i] = make_float4(0.f, 0.f, 0.f, 0.f);
}

__global__ __launch_bounds__(256) void scatter1_kernel(
    const float* __restrict__ x, const int* __restrict__ src,
    const int* __restrict__ dst, float* __restrict__ agg,
    float* __restrict__ cnt) {
    unsigned tid = blockIdx.x * 256u + threadIdx.x;
    unsigned e = tid >> 4, ch = tid & 15u;
    if (e >= NE) return;
    int s = src[e], d = dst[e];
    float4 v = *reinterpret_cast<const float4*>(x + (size_t)s * IND + ch * 4u);
    float* a = agg + (size_t)d * IND + ch * 4u;
    unsafeAtomicAdd(a + 0, v.x); unsafeAtomicAdd(a + 1, v.y);
    unsafeAtomicAdd(a + 2, v.z); unsafeAtomicAdd(a + 3, v.w);
    if (ch == 0) unsafeAtomicAdd(cnt + d, 1.0f);
}

__global__ __launch_bounds__(256) void scatter2_kernel(
    const float* __restrict__ h1, const int* __restrict__ src,
    const int* __restrict__ dst, float* __restrict__ agg) {
    unsigned tid = blockIdx.x * 256u + threadIdx.x;
    unsigned e = tid >> 5, ch = tid & 31u;
    if (e >= NE) return;
    int s = src[e], d = dst[e];
    float4 v = *reinterpret_cast<const float4*>(h1 + (size_t)s * HID + ch * 4u);
    float* a = agg + (size_t)d * HID + ch * 4u;
    unsafeAtomicAdd(a + 0, v.x); unsafeAtomicAdd(a + 1, v.y);
    unsafeAtomicAdd(a + 2, v.z); unsafeAtomicAdd(a + 3, v.w);
}

__global__ __launch_bounds__(128) void layer1_kernel(
    const float* __restrict__ x, const float* __restrict__ agg1,
    const float* __restrict__ cnt, const float* __restrict__ Wl,
    const float* __restrict__ Wr, const float* __restrict__ b,
    float* __restrict__ h1) {
    int i = blockIdx.x, j = threadIdx.x;
    __shared__ float sm[IND * 2];
    float ic = 1.0f / fmaxf(cnt[i], 1.0f);
    if (j < IND) sm[j] = x[(size_t)i * IND + j];
    else sm[j] = agg1[(size_t)i * IND + (j - IND)] * ic;
    __syncthreads();
    float acc = b[j];
    #pragma unroll
    for (int k = 0; k < IND; ++k)
        acc += sm[IND + k] * Wl[k * HID + j] + sm[k] * Wr[k * HID + j];
    h1[(size_t)i * HID + j] = fmaxf(acc, 0.0f);
}

__global__ __launch_bounds__(128) void layer2_kernel(
    const float* __restrict__ h1, float* __restrict__ h2,
    const float* __restrict__ cnt, const float* __restrict__ Wl,
    const float* __restrict__ Wr, const float* __restrict__ b,
    const float* __restrict__ Wout, const float* __restrict__ bout,
    float* __restrict__ out) {
    int i = blockIdx.x, j = threadIdx.x;
    __shared__ float sm[HID * 2];
    __shared__ float red[HID];
    float ic = 1.0f / fmaxf(cnt[i], 1.0f);
    sm[j] = h1[(size_t)i * HID + j];
    sm[HID + j] = h2[(size_t)i * HID + j] * ic;
    __syncthreads();
    float acc = b[j];
    #pragma unroll
    for (int k = 0; k < HID; ++k)
        acc += sm[HID + k] * Wl[k * HID + j] + sm[k] * Wr[k * HID + j];
    h2[(size_t)i * HID + j] = acc;
    red[j] = acc * Wout[j];
    __syncthreads();
    if (j < 64) {
        float v = red[j] + red[j + 64];
        #pragma unroll
        for (int off = 32; off > 0; off >>= 1) v += __shfl_down(v, off);
        if (j == 0) out[i] = v + bout[0];
    }
}

// ============================ launch ============================

extern "C" void kernel_launch(void* const* d_in, const int* in_sizes, int n_in,
                              void* d_out, int out_size, void* d_ws, size_t ws_size,
                              hipStream_t stream) {
    const float* x    = (const float*)d_in[0];
    const int*   eidx = (const int*)d_in[1];
    const int*   src  = eidx;
    const int*   dst  = eidx + NE;
    const float* Wl1  = (const float*)d_in[2];
    const float* Wr1  = (const float*)d_in[3];
    const float* b1   = (const float*)d_in[4];
    const float* Wl2  = (const float*)d_in[5];
    const float* Wr2  = (const float*)d_in[6];
    const float* b2   = (const float*)d_in[7];
    const float* Wout = (const float*)d_in[8];
    const float* bout = (const float*)d_in[9];

    float* out = (float*)d_out;
    float* h1  = out + NN;
    float* h2  = h1 + (size_t)NN * HID;

    const size_t need = ((size_t)3 * NN + 128 + NE) * sizeof(int);
    if (ws_size >= need) {
        int* cnt   = (int*)d_ws;       // [NN]
        int* off   = cnt + NN;         // [NN]
        int* cur   = off + NN;         // [NN]
        int* bsums = cur + NN;         // [128]
        int* srcs  = bsums + 128;      // [NE]

        zero_int_kernel<<<(NN / 4 + 255) / 256, 256, 0, stream>>>((int4*)cnt, NN / 4);
        hist_kernel<<<(NE + 255) / 256, 256, 0, stream>>>(dst, cnt);
        scanA_kernel<<<NSB, 256, 0, stream>>>(cnt, bsums);
        scanB_kernel<<<1, 1, 0, stream>>>(bsums);
        scanC_kernel<<<NSB, 256, 0, stream>>>(cnt, bsums, off, cur);
        fill_kernel<<<(NE + 255) / 256, 256, 0, stream>>>(src, dst, cur, srcs);

        agg1_kernel<<<NN / 4, 256, 0, stream>>>(x, srcs, off, cnt, h1);
        gemm1_kernel<<<NN / 16, 256, 0, stream>>>(x, Wl1, Wr1, b1, h1);
        agg2_kernel<<<NN / 2, 256, 0, stream>>>(h1, srcs, off, cnt, h2);
        gemm2_kernel<<<NN / 16, 256, 0, stream>>>(h1, Wl2, Wr2, b2, Wout, bout, h2, out);
    } else {
        // fallback: atomic scatter path (round-1)
        float* cntf = (float*)d_ws;
        zero4_kernel<<<(NN / 4 + 255) / 256, 256, 0, stream>>>((float4*)cntf, NN / 4);
        zero4_kernel<<<((NN * IND / 4) + 255) / 256, 256, 0, stream>>>((float4*)h2, NN * IND / 4);
        scatter1_kernel<<<(NE * 16) / 256, 256, 0, stream>>>(x, src, dst, h2, cntf);
        layer1_kernel<<<NN, 128, 0, stream>>>(x, h2, cntf, Wl1, Wr1, b1, h1);
        zero4_kernel<<<((NN * HID / 4) + 255) / 256, 256, 0, stream>>>((float4*)h2, NN * HID / 4);
        scatter2_kernel<<<(NE * 32) / 256, 256, 0, stream>>>(h1, src, dst, h2);
        layer2_kernel<<<NN, 128, 0, stream>>>(h1, h2, cntf, Wl2, Wr2, b2, Wout, bout, out);
    }
}

// Round 3
// 406.716 us; speedup vs baseline: 11.3931x; 2.4723x over previous
//
#include <hip/hip_runtime.h>

#define NN 100000
#define IND 64
#define HID 128
#define NE 1600000
#define SCAN_CHUNK 1024
#define NSB ((NN + SCAN_CHUNK - 1) / SCAN_CHUNK)   // 98 scan blocks

typedef __attribute__((ext_vector_type(8))) short bf16x8;
typedef __attribute__((ext_vector_type(4))) float f32x4;

static __device__ __forceinline__ unsigned short f2bf(float f) {
    unsigned u = __float_as_uint(f);
    u = (u + 0x7FFFu + ((u >> 16) & 1u)) >> 16;   // RNE
    return (unsigned short)u;
}
static __device__ __forceinline__ float bflo(unsigned u) { return __uint_as_float(u << 16); }
static __device__ __forceinline__ float bfhi(unsigned u) { return __uint_as_float(u & 0xFFFF0000u); }
static __device__ __forceinline__ unsigned pack2(float a, float b) {
    return (unsigned)f2bf(a) | ((unsigned)f2bf(b) << 16);
}

// ============================ CSR build ============================

__global__ __launch_bounds__(256) void zero_int_kernel(int4* __restrict__ p, int n4) {
    int i = blockIdx.x * 256 + threadIdx.x;
    if (i < n4) p[i] = make_int4(0, 0, 0, 0);
}

__global__ __launch_bounds__(256) void hist_kernel(const int* __restrict__ dst,
                                                   int* __restrict__ cnt) {
    int e = blockIdx.x * 256 + threadIdx.x;
    if (e < NE) atomicAdd(&cnt[dst[e]], 1);
}

__global__ __launch_bounds__(256) void scanA_kernel(const int* __restrict__ cnt,
                                                    int* __restrict__ bsums) {
    int b = blockIdx.x, t = threadIdx.x;
    int base = b * SCAN_CHUNK + t * 4;
    int s = 0;
    #pragma unroll
    for (int k = 0; k < 4; ++k) { int i = base + k; if (i < NN) s += cnt[i]; }
    #pragma unroll
    for (int o = 32; o > 0; o >>= 1) s += __shfl_down(s, o);
    __shared__ int wsum[4];
    if ((t & 63) == 0) wsum[t >> 6] = s;
    __syncthreads();
    if (t == 0) bsums[b] = wsum[0] + wsum[1] + wsum[2] + wsum[3];
}

__global__ void scanB_kernel(int* __restrict__ bsums) {
    int acc = 0;
    for (int i = 0; i < NSB; ++i) { int v = bsums[i]; bsums[i] = acc; acc += v; }
}

__global__ __launch_bounds__(256) void scanC_kernel(const int* __restrict__ cnt,
                                                    const int* __restrict__ bsums,
                                                    int* __restrict__ off,
                                                    int* __restrict__ cur) {
    int b = blockIdx.x, t = threadIdx.x;
    int lane = t & 63, w = t >> 6;
    int base = b * SCAN_CHUNK + t * 4;
    int v[4]; int s = 0;
    #pragma unroll
    for (int k = 0; k < 4; ++k) {
        int i = base + k;
        v[k] = (i < NN) ? cnt[i] : 0;
        s += v[k];
    }
    int inc = s;
    #pragma unroll
    for (int o = 1; o < 64; o <<= 1) {
        int xv = __shfl_up(inc, o);
        if (lane >= o) inc += xv;
    }
    __shared__ int wsum[4];
    if (lane == 63) wsum[w] = inc;
    __syncthreads();
    int wbase = 0;
    for (int i = 0; i < w; ++i) wbase += wsum[i];
    int ex = bsums[b] + wbase + (inc - s);
    #pragma unroll
    for (int k = 0; k < 4; ++k) {
        int i = base + k;
        if (i < NN) { off[i] = ex; cur[i] = ex; }
        ex += v[k];
    }
}

__global__ __launch_bounds__(256) void fill_kernel(const int* __restrict__ src,
                                                   const int* __restrict__ dst,
                                                   int* __restrict__ cur,
                                                   int* __restrict__ srcs) {
    int e = blockIdx.x * 256 + threadIdx.x;
    if (e < NE) {
        int p = atomicAdd(&cur[dst[e]], 1);
        srcs[p] = src[e];
    }
}

// ============================ bf16 conversion / packing ============================

__global__ __launch_bounds__(256) void cvt_x_kernel(const float4* __restrict__ x,
                                                    ushort4* __restrict__ xb) {
    int i = blockIdx.x * 256 + threadIdx.x;   // over NN*64/4 exact
    float4 v = x[i];
    ushort4 o;
    o.x = f2bf(v.x); o.y = f2bf(v.y); o.z = f2bf(v.z); o.w = f2bf(v.w);
    xb[i] = o;
}

// pack Wcat = [Wr(k<Khalf) ; Wl] into MFMA B-fragment order:
// index ((jt*KS+ks)*64+l)*8+i  <-  W[k = ks*32+(l>>4)*8+i][j = jt*16+(l&15)]
__global__ __launch_bounds__(256) void packW_kernel(const float* __restrict__ Wr,
                                                    const float* __restrict__ Wl,
                                                    int Khalf, int KS,
                                                    unsigned short* __restrict__ Wp) {
    int t = blockIdx.x * 256 + threadIdx.x;
    if (t >= 8 * KS * 64) return;
    int l  = t & 63;
    int ks = (t >> 6) % KS;
    int jt = t / (64 * KS);
    int j  = jt * 16 + (l & 15);
    int kb = ks * 32 + (l >> 4) * 8;
    unsigned short v[8];
    #pragma unroll
    for (int i = 0; i < 8; ++i) {
        int k = kb + i;
        float w = (k < Khalf) ? Wr[k * HID + j] : Wl[(k - Khalf) * HID + j];
        v[i] = f2bf(w);
    }
    ushort4 lo, hi;
    lo.x = v[0]; lo.y = v[1]; lo.z = v[2]; lo.w = v[3];
    hi.x = v[4]; hi.y = v[5]; hi.z = v[6]; hi.w = v[7];
    ushort4* d = reinterpret_cast<ushort4*>(Wp + (size_t)t * 8);
    d[0] = lo; d[1] = hi;
}

// ============================ gather means (bf16) ============================

// 64 dims per node = 32 uints; half-wave per edge-parity, 4 nodes per block
__global__ __launch_bounds__(256) void agg1_kernel(const unsigned short* __restrict__ xb,
                                                   const int* __restrict__ srcs,
                                                   const int* __restrict__ off,
                                                   const int* __restrict__ cnt,
                                                   unsigned short* __restrict__ m1b) {
    int t = threadIdx.x;
    int n = blockIdx.x * 4 + (t >> 6);
    int l = t & 63, ep = l >> 5, d = l & 31;
    int s0 = off[n], deg = cnt[n];
    float ax = 0.f, ay = 0.f;
    int e = ep;
    for (; e + 2 < deg; e += 4) {
        int sA = srcs[s0 + e], sB = srcs[s0 + e + 2];
        unsigned uA = *reinterpret_cast<const unsigned*>(xb + (size_t)sA * IND + d * 2);
        unsigned uB = *reinterpret_cast<const unsigned*>(xb + (size_t)sB * IND + d * 2);
        ax += bflo(uA) + bflo(uB);
        ay += bfhi(uA) + bfhi(uB);
    }
    for (; e < deg; e += 2) {
        int s = srcs[s0 + e];
        unsigned u = *reinterpret_cast<const unsigned*>(xb + (size_t)s * IND + d * 2);
        ax += bflo(u); ay += bfhi(u);
    }
    ax += __shfl_down(ax, 32);
    ay += __shfl_down(ay, 32);
    if (l < 32) {
        float inv = 1.f / fmaxf((float)deg, 1.f);
        *reinterpret_cast<unsigned*>(m1b + (size_t)n * IND + d * 2) = pack2(ax * inv, ay * inv);
    }
}

// 128 dims per node = 64 uints; one wave per node, 4-deep edge unroll
__global__ __launch_bounds__(256) void agg2_kernel(const unsigned short* __restrict__ h1b,
                                                   const int* __restrict__ srcs,
                                                   const int* __restrict__ off,
                                                   const int* __restrict__ cnt,
                                                   unsigned short* __restrict__ m2b) {
    int t = threadIdx.x;
    int n = blockIdx.x * 4 + (t >> 6);
    int d = t & 63;
    int s0 = off[n], deg = cnt[n];
    float ax = 0.f, ay = 0.f;
    int e = 0;
    for (; e + 3 < deg; e += 4) {
        int sA = srcs[s0 + e],     sB = srcs[s0 + e + 1];
        int sC = srcs[s0 + e + 2], sD = srcs[s0 + e + 3];
        unsigned uA = *reinterpret_cast<const unsigned*>(h1b + (size_t)sA * HID + d * 2);
        unsigned uB = *reinterpret_cast<const unsigned*>(h1b + (size_t)sB * HID + d * 2);
        unsigned uC = *reinterpret_cast<const unsigned*>(h1b + (size_t)sC * HID + d * 2);
        unsigned uD = *reinterpret_cast<const unsigned*>(h1b + (size_t)sD * HID + d * 2);
        ax += (bflo(uA) + bflo(uB)) + (bflo(uC) + bflo(uD));
        ay += (bfhi(uA) + bfhi(uB)) + (bfhi(uC) + bfhi(uD));
    }
    for (; e < deg; ++e) {
        int s = srcs[s0 + e];
        unsigned u = *reinterpret_cast<const unsigned*>(h1b + (size_t)s * HID + d * 2);
        ax += bflo(u); ay += bfhi(u);
    }
    float inv = 1.f / fmaxf((float)deg, 1.f);
    *reinterpret_cast<unsigned*>(m2b + (size_t)n * HID + d * 2) = pack2(ax * inv, ay * inv);
}

// ============================ MFMA dense layers ============================

// layer1: h1 = relu([xb | m1b] @ Wp1 + b1); 64 nodes/block, 4 waves, K=128
__global__ __launch_bounds__(256) void mfma1_kernel(const unsigned short* __restrict__ xb,
                                                    const unsigned short* __restrict__ m1b,
                                                    const unsigned short* __restrict__ Wp,
                                                    const float* __restrict__ b,
                                                    float* __restrict__ h1f,
                                                    unsigned short* __restrict__ h1b) {
    int t = threadIdx.x, w = t >> 6, l = t & 63;
    int row0 = blockIdx.x * 64 + w * 16;
    int arow = row0 + (l & 15); if (arow > NN - 1) arow = NN - 1;
    int kcol = (l >> 4) * 8;
    f32x4 acc[8];
    #pragma unroll
    for (int jt = 0; jt < 8; ++jt) { acc[jt][0] = 0.f; acc[jt][1] = 0.f; acc[jt][2] = 0.f; acc[jt][3] = 0.f; }
    #pragma unroll
    for (int ks = 0; ks < 4; ++ks) {
        const unsigned short* A = (ks < 2) ? xb : m1b;
        int c = (ks & 1) * 32 + kcol;
        bf16x8 a = *reinterpret_cast<const bf16x8*>(A + (size_t)arow * IND + c);
        #pragma unroll
        for (int jt = 0; jt < 8; ++jt) {
            bf16x8 bb = *reinterpret_cast<const bf16x8*>(Wp + ((size_t)(jt * 4 + ks) * 64 + l) * 8);
            acc[jt] = __builtin_amdgcn_mfma_f32_16x16x32_bf16(a, bb, acc[jt], 0, 0, 0);
        }
    }
    int rbase = row0 + (l >> 4) * 4;
    #pragma unroll
    for (int jt = 0; jt < 8; ++jt) {
        int col = jt * 16 + (l & 15);
        float bias = b[col];
        #pragma unroll
        for (int r = 0; r < 4; ++r) {
            int row = rbase + r;
            if (row < NN) {
                float v = fmaxf(acc[jt][r] + bias, 0.f);
                h1f[(size_t)row * HID + col] = v;
                h1b[(size_t)row * HID + col] = f2bf(v);
            }
        }
    }
}

// layer2 + head: h2 = [h1b | m2b] @ Wp2 + b2; out = h2 @ Wout + bout; K=256
__global__ __launch_bounds__(256) void mfma2_kernel(const unsigned short* __restrict__ h1b,
                                                    const unsigned short* __restrict__ m2b,
                                                    const unsigned short* __restrict__ Wp,
                                                    const float* __restrict__ b,
                                                    const float* __restrict__ Wout,
                                                    const float* __restrict__ bout,
                                                    float* __restrict__ h2f,
                                                    float* __restrict__ out) {
    int t = threadIdx.x, w = t >> 6, l = t & 63;
    int row0 = blockIdx.x * 64 + w * 16;
    int arow = row0 + (l & 15); if (arow > NN - 1) arow = NN - 1;
    int kcol = (l >> 4) * 8;
    f32x4 acc[8];
    #pragma unroll
    for (int jt = 0; jt < 8; ++jt) { acc[jt][0] = 0.f; acc[jt][1] = 0.f; acc[jt][2] = 0.f; acc[jt][3] = 0.f; }
    #pragma unroll
    for (int ks = 0; ks < 8; ++ks) {
        const unsigned short* A = (ks < 4) ? h1b : m2b;
        int c = (ks & 3) * 32 + kcol;
        bf16x8 a = *reinterpret_cast<const bf16x8*>(A + (size_t)arow * HID + c);
        #pragma unroll
        for (int jt = 0; jt < 8; ++jt) {
            bf16x8 bb = *reinterpret_cast<const bf16x8*>(Wp + ((size_t)(jt * 8 + ks) * 64 + l) * 8);
            acc[jt] = __builtin_amdgcn_mfma_f32_16x16x32_bf16(a, bb, acc[jt], 0, 0, 0);
        }
    }
    int rbase = row0 + (l >> 4) * 4;
    float hs0 = 0.f, hs1 = 0.f, hs2 = 0.f, hs3 = 0.f;
    #pragma unroll
    for (int jt = 0; jt < 8; ++jt) {
        int col = jt * 16 + (l & 15);
        float bias = b[col];
        float wo = Wout[col];
        #pragma unroll
        for (int r = 0; r < 4; ++r) {
            int row = rbase + r;
            float v = acc[jt][r] + bias;
            if (row < NN) h2f[(size_t)row * HID + col] = v;
            if (r == 0) hs0 += v * wo;
            else if (r == 1) hs1 += v * wo;
            else if (r == 2) hs2 += v * wo;
            else hs3 += v * wo;
        }
    }
    #pragma unroll
    for (int o = 1; o < 16; o <<= 1) {
        hs0 += __shfl_xor(hs0, o);
        hs1 += __shfl_xor(hs1, o);
        hs2 += __shfl_xor(hs2, o);
        hs3 += __shfl_xor(hs3, o);
    }
    if ((l & 15) == 0) {
        float bo = bout[0];
        if (rbase + 0 < NN) out[rbase + 0] = hs0 + bo;
        if (rbase + 1 < NN) out[rbase + 1] = hs1 + bo;
        if (rbase + 2 < NN) out[rbase + 2] = hs2 + bo;
        if (rbase + 3 < NN) out[rbase + 3] = hs3 + bo;
    }
}

// ===================== fallback path (round-2, fp32 CSR) =====================

__global__ __launch_bounds__(256) void agg1f_kernel(const float* __restrict__ x,
                                                    const int* __restrict__ srcs,
                                                    const int* __restrict__ off,
                                                    const int* __restrict__ cnt,
                                                    float* __restrict__ mean1) {
    int t = threadIdx.x;
    int n = blockIdx.x * 4 + (t >> 6);
    int d = t & 63;
    int s0 = off[n], deg = cnt[n];
    float acc = 0.f;
    for (int e = 0; e < deg; ++e) acc += x[(size_t)srcs[s0 + e] * IND + d];
    mean1[(size_t)n * HID + d] = acc / fmaxf((float)deg, 1.f);
}

__global__ __launch_bounds__(256) void agg2f_kernel(const float* __restrict__ h1,
                                                    const int* __restrict__ srcs,
                                                    const int* __restrict__ off,
                                                    const int* __restrict__ cnt,
                                                    float* __restrict__ mean2) {
    int t = threadIdx.x;
    int n = blockIdx.x * 2 + (t >> 7);
    int d = t & 127;
    int s0 = off[n], deg = cnt[n];
    float acc = 0.f;
    for (int e = 0; e < deg; ++e) acc += h1[(size_t)srcs[s0 + e] * HID + d];
    mean2[(size_t)n * HID + d] = acc / fmaxf((float)deg, 1.f);
}

__global__ __launch_bounds__(256) void gemm1f_kernel(const float* __restrict__ x,
                                                     const float* __restrict__ Wl,
                                                     const float* __restrict__ Wr,
                                                     const float* __restrict__ b,
                                                     float* __restrict__ h1) {
    __shared__ float in[16][128];
    int t = threadIdx.x;
    int node0 = blockIdx.x * 16;
    for (int idx = t; idx < 16 * 128; idx += 256) {
        int r = idx >> 7, c = idx & 127;
        in[r][c] = (c < IND) ? x[(size_t)(node0 + r) * IND + c]
                             : h1[(size_t)(node0 + r) * HID + (c - IND)];
    }
    __syncthreads();
    int j = t & 127, g = t >> 7;
    float acc[8];
    float bj = b[j];
    #pragma unroll
    for (int q = 0; q < 8; ++q) acc[q] = bj;
    for (int k = 0; k < 128; ++k) {
        float wv = (k < IND) ? Wr[k * HID + j] : Wl[(k - IND) * HID + j];
        #pragma unroll
        for (int q = 0; q < 8; ++q) acc[q] += in[g * 8 + q][k] * wv;
    }
    #pragma unroll
    for (int q = 0; q < 8; ++q)
        h1[(size_t)(node0 + g * 8 + q) * HID + j] = fmaxf(acc[q], 0.f);
}

__global__ __launch_bounds__(256) void gemm2f_kernel(const float* __restrict__ h1,
                                                     const float* __restrict__ Wl,
                                                     const float* __restrict__ Wr,
                                                     const float* __restrict__ b,
                                                     const float* __restrict__ Wout,
                                                     const float* __restrict__ bout,
                                                     float* __restrict__ h2,
                                                     float* __restrict__ out) {
    __shared__ float in[16][256];
    __shared__ float part[4][8];
    int t = threadIdx.x;
    int node0 = blockIdx.x * 16;
    for (int idx = t; idx < 16 * 256; idx += 256) {
        int r = idx >> 8, c = idx & 255;
        in[r][c] = (c < HID) ? h1[(size_t)(node0 + r) * HID + c]
                             : h2[(size_t)(node0 + r) * HID + (c - HID)];
    }
    __syncthreads();
    int j = t & 127, g = t >> 7, lane = t & 63, w = t >> 6;
    float acc[8];
    float bj = b[j];
    #pragma unroll
    for (int q = 0; q < 8; ++q) acc[q] = bj;
    for (int k = 0; k < 256; ++k) {
        float wv = (k < HID) ? Wr[k * HID + j] : Wl[(k - HID) * HID + j];
        #pragma unroll
        for (int q = 0; q < 8; ++q) acc[q] += in[g * 8 + q][k] * wv;
    }
    float wo = Wout[j];
    #pragma unroll
    for (int q = 0; q < 8; ++q)
        h2[(size_t)(node0 + g * 8 + q) * HID + j] = acc[q];
    #pragma unroll
    for (int q = 0; q < 8; ++q) {
        float v = acc[q] * wo;
        #pragma unroll
        for (int o = 32; o > 0; o >>= 1) v += __shfl_down(v, o);
        if (lane == 0) part[w][q] = v;
    }
    __syncthreads();
    if (t < 16) {
        int gg = t >> 3, q = t & 7;
        out[node0 + t] = part[2 * gg][q] + part[2 * gg + 1][q] + bout[0];
    }
}

// ============================ launch ============================

extern "C" void kernel_launch(void* const* d_in, const int* in_sizes, int n_in,
                              void* d_out, int out_size, void* d_ws, size_t ws_size,
                              hipStream_t stream) {
    const float* x    = (const float*)d_in[0];
    const int*   eidx = (const int*)d_in[1];
    const int*   src  = eidx;
    const int*   dst  = eidx + NE;
    const float* Wl1  = (const float*)d_in[2];
    const float* Wr1  = (const float*)d_in[3];
    const float* b1   = (const float*)d_in[4];
    const float* Wl2  = (const float*)d_in[5];
    const float* Wr2  = (const float*)d_in[6];
    const float* b2   = (const float*)d_in[7];
    const float* Wout = (const float*)d_in[8];
    const float* bout = (const float*)d_in[9];

    float* out = (float*)d_out;
    float* h1f = out + NN;
    float* h2f = h1f + (size_t)NN * HID;

    // ---- workspace layout ----
    char* p = (char*)d_ws;
    int* cnt   = (int*)p;                 p += (size_t)NN * 4;        // 400000
    int* off   = (int*)p;                 p += (size_t)NN * 4;
    int* cur   = (int*)p;                 p += (size_t)NN * 4;
    int* bsums = (int*)p;                 p += 512;
    int* srcs  = (int*)p;                 p += (size_t)NE * 4;        // 6.4MB
    unsigned short* xb  = (unsigned short*)p;  p += (size_t)NN * IND * 2;   // 12.8MB
    unsigned short* m1b = (unsigned short*)p;  p += (size_t)NN * IND * 2;   // 12.8MB
    unsigned short* h1b = (unsigned short*)p;  p += (size_t)NN * HID * 2;   // 25.6MB
    unsigned short* m2b = (unsigned short*)p;  p += (size_t)NN * HID * 2;   // 25.6MB
    unsigned short* Wp1 = (unsigned short*)p;  p += 8 * 4 * 64 * 8 * 2;     // 32KB
    unsigned short* Wp2 = (unsigned short*)p;  p += 8 * 8 * 64 * 8 * 2;     // 64KB
    const size_t need_full = (size_t)(p - (char*)d_ws);
    const size_t need_csr  = ((size_t)3 * NN + 128 + NE) * sizeof(int);

    if (ws_size >= need_full) {
        // CSR build
        zero_int_kernel<<<(NN / 4 + 255) / 256, 256, 0, stream>>>((int4*)cnt, NN / 4);
        hist_kernel<<<(NE + 255) / 256, 256, 0, stream>>>(dst, cnt);
        scanA_kernel<<<NSB, 256, 0, stream>>>(cnt, bsums);
        scanB_kernel<<<1, 1, 0, stream>>>(bsums);
        scanC_kernel<<<NSB, 256, 0, stream>>>(cnt, bsums, off, cur);
        fill_kernel<<<(NE + 255) / 256, 256, 0, stream>>>(src, dst, cur, srcs);
        // bf16 conversions / weight packing
        cvt_x_kernel<<<(NN * IND / 4) / 256, 256, 0, stream>>>((const float4*)x, (ushort4*)xb);
        packW_kernel<<<8, 256, 0, stream>>>(Wr1, Wl1, IND, 4, Wp1);
        packW_kernel<<<16, 256, 0, stream>>>(Wr2, Wl2, HID, 8, Wp2);
        // layer 1
        agg1_kernel<<<NN / 4, 256, 0, stream>>>(xb, srcs, off, cnt, m1b);
        mfma1_kernel<<<(NN + 63) / 64, 256, 0, stream>>>(xb, m1b, Wp1, b1, h1f, h1b);
        // layer 2 + head
        agg2_kernel<<<NN / 4, 256, 0, stream>>>(h1b, srcs, off, cnt, m2b);
        mfma2_kernel<<<(NN + 63) / 64, 256, 0, stream>>>(h1b, m2b, Wp2, b2, Wout, bout, h2f, out);
    } else if (ws_size >= need_csr) {
        // round-2 fp32 CSR path
        zero_int_kernel<<<(NN / 4 + 255) / 256, 256, 0, stream>>>((int4*)cnt, NN / 4);
        hist_kernel<<<(NE + 255) / 256, 256, 0, stream>>>(dst, cnt);
        scanA_kernel<<<NSB, 256, 0, stream>>>(cnt, bsums);
        scanB_kernel<<<1, 1, 0, stream>>>(bsums);
        scanC_kernel<<<NSB, 256, 0, stream>>>(cnt, bsums, off, cur);
        fill_kernel<<<(NE + 255) / 256, 256, 0, stream>>>(src, dst, cur, srcs);
        agg1f_kernel<<<NN / 4, 256, 0, stream>>>(x, srcs, off, cnt, h1f);
        gemm1f_kernel<<<NN / 16, 256, 0, stream>>>(x, Wl1, Wr1, b1, h1f);
        agg2f_kernel<<<NN / 2, 256, 0, stream>>>(h1f, srcs, off, cnt, h2f);
        gemm2f_kernel<<<NN / 16, 256, 0, stream>>>(h1f, Wl2, Wr2, b2, Wout, bout, h2f, out);
    }
}

// Round 4
// 259.146 us; speedup vs baseline: 17.8810x; 1.5695x over previous
//
#include <hip/hip_runtime.h>

#define NN 100000
#define IND 64
#define HID 128
#define NE 1600000
#define SCAN_CHUNK 1024
#define NSB ((NN + SCAN_CHUNK - 1) / SCAN_CHUNK)   // 98 scan blocks (fallback path)

#define BKT_SHIFT 9
#define BKT_NODES 512
#define NBKT ((NN + BKT_NODES - 1) / BKT_NODES)    // 196 buckets
#define EPB 8192
#define NBLK_E ((NE + EPB - 1) / EPB)              // 196 edge chunks

typedef __attribute__((ext_vector_type(8))) short bf16x8;
typedef __attribute__((ext_vector_type(4))) float f32x4;

static __device__ __forceinline__ unsigned short f2bf(float f) {
    unsigned u = __float_as_uint(f);
    u = (u + 0x7FFFu + ((u >> 16) & 1u)) >> 16;   // RNE
    return (unsigned short)u;
}
static __device__ __forceinline__ float bflo(unsigned u) { return __uint_as_float(u << 16); }
static __device__ __forceinline__ float bfhi(unsigned u) { return __uint_as_float(u & 0xFFFF0000u); }
static __device__ __forceinline__ unsigned pack2(float a, float b) {
    return (unsigned)f2bf(a) | ((unsigned)f2bf(b) << 16);
}

// ===================== CSR build v2: two-level binning =====================

__global__ __launch_bounds__(256) void zero_small_kernel(int* __restrict__ p, int n) {
    int i = threadIdx.x;
    if (i < n) p[i] = 0;
}

// per-chunk LDS histogram over 196 buckets -> global bucket counts
__global__ __launch_bounds__(512) void bucket_hist_kernel(const int* __restrict__ dst,
                                                          int* __restrict__ bcnt) {
    __shared__ int bh[NBKT];
    int t = threadIdx.x;
    int e0 = blockIdx.x * EPB;
    int ce = min(EPB, NE - e0);
    if (t < NBKT) bh[t] = 0;
    __syncthreads();
    for (int i = t; i < ce; i += 512)
        atomicAdd(&bh[dst[e0 + i] >> BKT_SHIFT], 1);
    __syncthreads();
    if (t < NBKT) { int c = bh[t]; if (c) atomicAdd(&bcnt[t], c); }
}

// single-wave exclusive scan of 196 bucket counts -> bbase[NBKT+1], bktcur
__global__ void bucket_scan_kernel(const int* __restrict__ bcnt,
                                   int* __restrict__ bbase,
                                   int* __restrict__ bktcur) {
    int t = threadIdx.x;   // 64 threads
    int carry = 0;
    #pragma unroll
    for (int c = 0; c < 4; ++c) {
        int idx = c * 64 + t;
        int v = (idx < NBKT) ? bcnt[idx] : 0;
        int incl = v;
        #pragma unroll
        for (int o = 1; o < 64; o <<= 1) {
            int u = __shfl_up(incl, o);
            if (t >= o) incl += u;
        }
        int ex = carry + incl - v;
        if (idx < NBKT) { bbase[idx] = ex; bktcur[idx] = ex; }
        carry += __shfl(incl, 63);
    }
    if (t == 0) bbase[NBKT] = carry;
}

// Phase A: bin edges into bucket regions as packed (dstlow<<17 | src)
__global__ __launch_bounds__(512) void binA_kernel(const int* __restrict__ src,
                                                   const int* __restrict__ dst,
                                                   int* __restrict__ bktcur,
                                                   unsigned* __restrict__ bsrc) {
    __shared__ int hcnt[NBKT];
    __shared__ int rbase[NBKT];
    int t = threadIdx.x;
    int e0 = blockIdx.x * EPB;
    int ce = min(EPB, NE - e0);
    if (t < NBKT) hcnt[t] = 0;
    __syncthreads();
    for (int i = t; i < ce; i += 512)
        atomicAdd(&hcnt[dst[e0 + i] >> BKT_SHIFT], 1);
    __syncthreads();
    if (t < NBKT) {
        int c = hcnt[t];
        rbase[t] = c ? atomicAdd(&bktcur[t], c) : 0;
        hcnt[t] = 0;
    }
    __syncthreads();
    for (int i = t; i < ce; i += 512) {
        int d = dst[e0 + i];
        int b = d >> BKT_SHIFT;
        int r = atomicAdd(&hcnt[b], 1);
        bsrc[rbase[b] + r] = (unsigned)src[e0 + i] | ((unsigned)(d & (BKT_NODES - 1)) << 17);
    }
}

// Phase B: per-bucket exact CSR fill + per-node cnt/off (coalesced)
__global__ __launch_bounds__(512) void binB_kernel(const unsigned* __restrict__ bsrc,
                                                   const int* __restrict__ bbase,
                                                   int* __restrict__ cnt,
                                                   int* __restrict__ off,
                                                   int* __restrict__ srcs) {
    __shared__ int ncnt[BKT_NODES];
    __shared__ int nofs[BKT_NODES];
    __shared__ int wtot[8];
    int t = threadIdx.x, lane = t & 63, w = t >> 6;
    int b = blockIdx.x;
    int ebase = bbase[b], m = bbase[b + 1] - ebase;
    int nb0 = b * BKT_NODES;
    ncnt[t] = 0;
    __syncthreads();
    for (int i = t; i < m; i += 512)
        atomicAdd(&ncnt[bsrc[ebase + i] >> 17], 1);
    __syncthreads();
    int v = ncnt[t];
    int incl = v;
    #pragma unroll
    for (int o = 1; o < 64; o <<= 1) {
        int u = __shfl_up(incl, o);
        if (lane >= o) incl += u;
    }
    if (lane == 63) wtot[w] = incl;
    __syncthreads();
    int wbase = 0;
    #pragma unroll
    for (int i = 0; i < 8; ++i) if (i < w) wbase += wtot[i];
    int ex = wbase + incl - v;
    nofs[t] = ex;
    int node = nb0 + t;
    if (node < NN) { off[node] = ebase + ex; cnt[node] = v; }
    __syncthreads();
    for (int i = t; i < m; i += 512) {
        unsigned val = bsrc[ebase + i];
        int nl = val >> 17;
        int r = atomicAdd(&nofs[nl], 1);
        srcs[ebase + r] = (int)(val & 0x1FFFFu);
    }
}

// ===================== CSR build v1 (fallback) =====================

__global__ __launch_bounds__(256) void zero_int_kernel(int4* __restrict__ p, int n4) {
    int i = blockIdx.x * 256 + threadIdx.x;
    if (i < n4) p[i] = make_int4(0, 0, 0, 0);
}

__global__ __launch_bounds__(256) void hist_kernel(const int* __restrict__ dst,
                                                   int* __restrict__ cnt) {
    int e = blockIdx.x * 256 + threadIdx.x;
    if (e < NE) atomicAdd(&cnt[dst[e]], 1);
}

__global__ __launch_bounds__(256) void scanA_kernel(const int* __restrict__ cnt,
                                                    int* __restrict__ bsums) {
    int b = blockIdx.x, t = threadIdx.x;
    int base = b * SCAN_CHUNK + t * 4;
    int s = 0;
    #pragma unroll
    for (int k = 0; k < 4; ++k) { int i = base + k; if (i < NN) s += cnt[i]; }
    #pragma unroll
    for (int o = 32; o > 0; o >>= 1) s += __shfl_down(s, o);
    __shared__ int wsum[4];
    if ((t & 63) == 0) wsum[t >> 6] = s;
    __syncthreads();
    if (t == 0) bsums[b] = wsum[0] + wsum[1] + wsum[2] + wsum[3];
}

__global__ void scanB_kernel(int* __restrict__ bsums) {
    int acc = 0;
    for (int i = 0; i < NSB; ++i) { int v = bsums[i]; bsums[i] = acc; acc += v; }
}

__global__ __launch_bounds__(256) void scanC_kernel(const int* __restrict__ cnt,
                                                    const int* __restrict__ bsums,
                                                    int* __restrict__ off,
                                                    int* __restrict__ cur) {
    int b = blockIdx.x, t = threadIdx.x;
    int lane = t & 63, w = t >> 6;
    int base = b * SCAN_CHUNK + t * 4;
    int v[4]; int s = 0;
    #pragma unroll
    for (int k = 0; k < 4; ++k) {
        int i = base + k;
        v[k] = (i < NN) ? cnt[i] : 0;
        s += v[k];
    }
    int inc = s;
    #pragma unroll
    for (int o = 1; o < 64; o <<= 1) {
        int xv = __shfl_up(inc, o);
        if (lane >= o) inc += xv;
    }
    __shared__ int wsum[4];
    if (lane == 63) wsum[w] = inc;
    __syncthreads();
    int wbase = 0;
    for (int i = 0; i < w; ++i) wbase += wsum[i];
    int ex = bsums[b] + wbase + (inc - s);
    #pragma unroll
    for (int k = 0; k < 4; ++k) {
        int i = base + k;
        if (i < NN) { off[i] = ex; cur[i] = ex; }
        ex += v[k];
    }
}

__global__ __launch_bounds__(256) void fill_kernel(const int* __restrict__ src,
                                                   const int* __restrict__ dst,
                                                   int* __restrict__ cur,
                                                   int* __restrict__ srcs) {
    int e = blockIdx.x * 256 + threadIdx.x;
    if (e < NE) {
        int p = atomicAdd(&cur[dst[e]], 1);
        srcs[p] = src[e];
    }
}

// ============================ bf16 conversion / packing ============================

__global__ __launch_bounds__(256) void cvt_x_kernel(const float4* __restrict__ x,
                                                    ushort4* __restrict__ xb) {
    int i = blockIdx.x * 256 + threadIdx.x;   // over NN*64/4 exact
    float4 v = x[i];
    ushort4 o;
    o.x = f2bf(v.x); o.y = f2bf(v.y); o.z = f2bf(v.z); o.w = f2bf(v.w);
    xb[i] = o;
}

// pack Wcat = [Wr(k<Khalf) ; Wl] into MFMA B-fragment order
__global__ __launch_bounds__(256) void packW_kernel(const float* __restrict__ Wr,
                                                    const float* __restrict__ Wl,
                                                    int Khalf, int KS,
                                                    unsigned short* __restrict__ Wp) {
    int t = blockIdx.x * 256 + threadIdx.x;
    if (t >= 8 * KS * 64) return;
    int l  = t & 63;
    int ks = (t >> 6) % KS;
    int jt = t / (64 * KS);
    int j  = jt * 16 + (l & 15);
    int kb = ks * 32 + (l >> 4) * 8;
    unsigned short v[8];
    #pragma unroll
    for (int i = 0; i < 8; ++i) {
        int k = kb + i;
        float w = (k < Khalf) ? Wr[k * HID + j] : Wl[(k - Khalf) * HID + j];
        v[i] = f2bf(w);
    }
    ushort4 lo, hi;
    lo.x = v[0]; lo.y = v[1]; lo.z = v[2]; lo.w = v[3];
    hi.x = v[4]; hi.y = v[5]; hi.z = v[6]; hi.w = v[7];
    ushort4* d = reinterpret_cast<ushort4*>(Wp + (size_t)t * 8);
    d[0] = lo; d[1] = hi;
}

// ============================ gather means (bf16) ============================

__global__ __launch_bounds__(256) void agg1_kernel(const unsigned short* __restrict__ xb,
                                                   const int* __restrict__ srcs,
                                                   const int* __restrict__ off,
                                                   const int* __restrict__ cnt,
                                                   unsigned short* __restrict__ m1b) {
    int t = threadIdx.x;
    int n = blockIdx.x * 4 + (t >> 6);
    int l = t & 63, ep = l >> 5, d = l & 31;
    int s0 = off[n], deg = cnt[n];
    float ax = 0.f, ay = 0.f;
    int e = ep;
    for (; e + 2 < deg; e += 4) {
        int sA = srcs[s0 + e], sB = srcs[s0 + e + 2];
        unsigned uA = *reinterpret_cast<const unsigned*>(xb + (size_t)sA * IND + d * 2);
        unsigned uB = *reinterpret_cast<const unsigned*>(xb + (size_t)sB * IND + d * 2);
        ax += bflo(uA) + bflo(uB);
        ay += bfhi(uA) + bfhi(uB);
    }
    for (; e < deg; e += 2) {
        int s = srcs[s0 + e];
        unsigned u = *reinterpret_cast<const unsigned*>(xb + (size_t)s * IND + d * 2);
        ax += bflo(u); ay += bfhi(u);
    }
    ax += __shfl_down(ax, 32);
    ay += __shfl_down(ay, 32);
    if (l < 32) {
        float inv = 1.f / fmaxf((float)deg, 1.f);
        *reinterpret_cast<unsigned*>(m1b + (size_t)n * IND + d * 2) = pack2(ax * inv, ay * inv);
    }
}

__global__ __launch_bounds__(256) void agg2_kernel(const unsigned short* __restrict__ h1b,
                                                   const int* __restrict__ srcs,
                                                   const int* __restrict__ off,
                                                   const int* __restrict__ cnt,
                                                   unsigned short* __restrict__ m2b) {
    int t = threadIdx.x;
    int n = blockIdx.x * 4 + (t >> 6);
    int d = t & 63;
    int s0 = off[n], deg = cnt[n];
    float ax = 0.f, ay = 0.f;
    int e = 0;
    for (; e + 3 < deg; e += 4) {
        int sA = srcs[s0 + e],     sB = srcs[s0 + e + 1];
        int sC = srcs[s0 + e + 2], sD = srcs[s0 + e + 3];
        unsigned uA = *reinterpret_cast<const unsigned*>(h1b + (size_t)sA * HID + d * 2);
        unsigned uB = *reinterpret_cast<const unsigned*>(h1b + (size_t)sB * HID + d * 2);
        unsigned uC = *reinterpret_cast<const unsigned*>(h1b + (size_t)sC * HID + d * 2);
        unsigned uD = *reinterpret_cast<const unsigned*>(h1b + (size_t)sD * HID + d * 2);
        ax += (bflo(uA) + bflo(uB)) + (bflo(uC) + bflo(uD));
        ay += (bfhi(uA) + bfhi(uB)) + (bfhi(uC) + bfhi(uD));
    }
    for (; e < deg; ++e) {
        int s = srcs[s0 + e];
        unsigned u = *reinterpret_cast<const unsigned*>(h1b + (size_t)s * HID + d * 2);
        ax += bflo(u); ay += bfhi(u);
    }
    float inv = 1.f / fmaxf((float)deg, 1.f);
    *reinterpret_cast<unsigned*>(m2b + (size_t)n * HID + d * 2) = pack2(ax * inv, ay * inv);
}

// ============================ MFMA dense layers ============================

__global__ __launch_bounds__(256) void mfma1_kernel(const unsigned short* __restrict__ xb,
                                                    const unsigned short* __restrict__ m1b,
                                                    const unsigned short* __restrict__ Wp,
                                                    const float* __restrict__ b,
                                                    float* __restrict__ h1f,
                                                    unsigned short* __restrict__ h1b) {
    int t = threadIdx.x, w = t >> 6, l = t & 63;
    int row0 = blockIdx.x * 64 + w * 16;
    int arow = row0 + (l & 15); if (arow > NN - 1) arow = NN - 1;
    int kcol = (l >> 4) * 8;
    f32x4 acc[8];
    #pragma unroll
    for (int jt = 0; jt < 8; ++jt) { acc[jt][0] = 0.f; acc[jt][1] = 0.f; acc[jt][2] = 0.f; acc[jt][3] = 0.f; }
    #pragma unroll
    for (int ks = 0; ks < 4; ++ks) {
        const unsigned short* A = (ks < 2) ? xb : m1b;
        int c = (ks & 1) * 32 + kcol;
        bf16x8 a = *reinterpret_cast<const bf16x8*>(A + (size_t)arow * IND + c);
        #pragma unroll
        for (int jt = 0; jt < 8; ++jt) {
            bf16x8 bb = *reinterpret_cast<const bf16x8*>(Wp + ((size_t)(jt * 4 + ks) * 64 + l) * 8);
            acc[jt] = __builtin_amdgcn_mfma_f32_16x16x32_bf16(a, bb, acc[jt], 0, 0, 0);
        }
    }
    int rbase = row0 + (l >> 4) * 4;
    #pragma unroll
    for (int jt = 0; jt < 8; ++jt) {
        int col = jt * 16 + (l & 15);
        float bias = b[col];
        #pragma unroll
        for (int r = 0; r < 4; ++r) {
            int row = rbase + r;
            if (row < NN) {
                float v = fmaxf(acc[jt][r] + bias, 0.f);
                h1f[(size_t)row * HID + col] = v;
                h1b[(size_t)row * HID + col] = f2bf(v);
            }
        }
    }
}

__global__ __launch_bounds__(256) void mfma2_kernel(const unsigned short* __restrict__ h1b,
                                                    const unsigned short* __restrict__ m2b,
                                                    const unsigned short* __restrict__ Wp,
                                                    const float* __restrict__ b,
                                                    const float* __restrict__ Wout,
                                                    const float* __restrict__ bout,
                                                    float* __restrict__ h2f,
                                                    float* __restrict__ out) {
    int t = threadIdx.x, w = t >> 6, l = t & 63;
    int row0 = blockIdx.x * 64 + w * 16;
    int arow = row0 + (l & 15); if (arow > NN - 1) arow = NN - 1;
    int kcol = (l >> 4) * 8;
    f32x4 acc[8];
    #pragma unroll
    for (int jt = 0; jt < 8; ++jt) { acc[jt][0] = 0.f; acc[jt][1] = 0.f; acc[jt][2] = 0.f; acc[jt][3] = 0.f; }
    #pragma unroll
    for (int ks = 0; ks < 8; ++ks) {
        const unsigned short* A = (ks < 4) ? h1b : m2b;
        int c = (ks & 3) * 32 + kcol;
        bf16x8 a = *reinterpret_cast<const bf16x8*>(A + (size_t)arow * HID + c);
        #pragma unroll
        for (int jt = 0; jt < 8; ++jt) {
            bf16x8 bb = *reinterpret_cast<const bf16x8*>(Wp + ((size_t)(jt * 8 + ks) * 64 + l) * 8);
            acc[jt] = __builtin_amdgcn_mfma_f32_16x16x32_bf16(a, bb, acc[jt], 0, 0, 0);
        }
    }
    int rbase = row0 + (l >> 4) * 4;
    float hs0 = 0.f, hs1 = 0.f, hs2 = 0.f, hs3 = 0.f;
    #pragma unroll
    for (int jt = 0; jt < 8; ++jt) {
        int col = jt * 16 + (l & 15);
        float bias = b[col];
        float wo = Wout[col];
        #pragma unroll
        for (int r = 0; r < 4; ++r) {
            int row = rbase + r;
            float v = acc[jt][r] + bias;
            if (row < NN) h2f[(size_t)row * HID + col] = v;
            if (r == 0) hs0 += v * wo;
            else if (r == 1) hs1 += v * wo;
            else if (r == 2) hs2 += v * wo;
            else hs3 += v * wo;
        }
    }
    #pragma unroll
    for (int o = 1; o < 16; o <<= 1) {
        hs0 += __shfl_xor(hs0, o);
        hs1 += __shfl_xor(hs1, o);
        hs2 += __shfl_xor(hs2, o);
        hs3 += __shfl_xor(hs3, o);
    }
    if ((l & 15) == 0) {
        float bo = bout[0];
        if (rbase + 0 < NN) out[rbase + 0] = hs0 + bo;
        if (rbase + 1 < NN) out[rbase + 1] = hs1 + bo;
        if (rbase + 2 < NN) out[rbase + 2] = hs2 + bo;
        if (rbase + 3 < NN) out[rbase + 3] = hs3 + bo;
    }
}

// ===================== fp32 fallback path (round-2) =====================

__global__ __launch_bounds__(256) void agg1f_kernel(const float* __restrict__ x,
                                                    const int* __restrict__ srcs,
                                                    const int* __restrict__ off,
                                                    const int* __restrict__ cnt,
                                                    float* __restrict__ mean1) {
    int t = threadIdx.x;
    int n = blockIdx.x * 4 + (t >> 6);
    int d = t & 63;
    int s0 = off[n], deg = cnt[n];
    float acc = 0.f;
    for (int e = 0; e < deg; ++e) acc += x[(size_t)srcs[s0 + e] * IND + d];
    mean1[(size_t)n * HID + d] = acc / fmaxf((float)deg, 1.f);
}

__global__ __launch_bounds__(256) void agg2f_kernel(const float* __restrict__ h1,
                                                    const int* __restrict__ srcs,
                                                    const int* __restrict__ off,
                                                    const int* __restrict__ cnt,
                                                    float* __restrict__ mean2) {
    int t = threadIdx.x;
    int n = blockIdx.x * 2 + (t >> 7);
    int d = t & 127;
    int s0 = off[n], deg = cnt[n];
    float acc = 0.f;
    for (int e = 0; e < deg; ++e) acc += h1[(size_t)srcs[s0 + e] * HID + d];
    mean2[(size_t)n * HID + d] = acc / fmaxf((float)deg, 1.f);
}

__global__ __launch_bounds__(256) void gemm1f_kernel(const float* __restrict__ x,
                                                     const float* __restrict__ Wl,
                                                     const float* __restrict__ Wr,
                                                     const float* __restrict__ b,
                                                     float* __restrict__ h1) {
    __shared__ float in[16][128];
    int t = threadIdx.x;
    int node0 = blockIdx.x * 16;
    for (int idx = t; idx < 16 * 128; idx += 256) {
        int r = idx >> 7, c = idx & 127;
        in[r][c] = (c < IND) ? x[(size_t)(node0 + r) * IND + c]
                             : h1[(size_t)(node0 + r) * HID + (c - IND)];
    }
    __syncthreads();
    int j = t & 127, g = t >> 7;
    float acc[8];
    float bj = b[j];
    #pragma unroll
    for (int q = 0; q < 8; ++q) acc[q] = bj;
    for (int k = 0; k < 128; ++k) {
        float wv = (k < IND) ? Wr[k * HID + j] : Wl[(k - IND) * HID + j];
        #pragma unroll
        for (int q = 0; q < 8; ++q) acc[q] += in[g * 8 + q][k] * wv;
    }
    #pragma unroll
    for (int q = 0; q < 8; ++q)
        h1[(size_t)(node0 + g * 8 + q) * HID + j] = fmaxf(acc[q], 0.f);
}

__global__ __launch_bounds__(256) void gemm2f_kernel(const float* __restrict__ h1,
                                                     const float* __restrict__ Wl,
                                                     const float* __restrict__ Wr,
                                                     const float* __restrict__ b,
                                                     const float* __restrict__ Wout,
                                                     const float* __restrict__ bout,
                                                     float* __restrict__ h2,
                                                     float* __restrict__ out) {
    __shared__ float in[16][256];
    __shared__ float part[4][8];
    int t = threadIdx.x;
    int node0 = blockIdx.x * 16;
    for (int idx = t; idx < 16 * 256; idx += 256) {
        int r = idx >> 8, c = idx & 255;
        in[r][c] = (c < HID) ? h1[(size_t)(node0 + r) * HID + c]
                             : h2[(size_t)(node0 + r) * HID + (c - HID)];
    }
    __syncthreads();
    int j = t & 127, g = t >> 7, lane = t & 63, w = t >> 6;
    float acc[8];
    float bj = b[j];
    #pragma unroll
    for (int q = 0; q < 8; ++q) acc[q] = bj;
    for (int k = 0; k < 256; ++k) {
        float wv = (k < HID) ? Wr[k * HID + j] : Wl[(k - HID) * HID + j];
        #pragma unroll
        for (int q = 0; q < 8; ++q) acc[q] += in[g * 8 + q][k] * wv;
    }
    float wo = Wout[j];
    #pragma unroll
    for (int q = 0; q < 8; ++q)
        h2[(size_t)(node0 + g * 8 + q) * HID + j] = acc[q];
    #pragma unroll
    for (int q = 0; q < 8; ++q) {
        float v = acc[q] * wo;
        #pragma unroll
        for (int o = 32; o > 0; o >>= 1) v += __shfl_down(v, o);
        if (lane == 0) part[w][q] = v;
    }
    __syncthreads();
    if (t < 16) {
        int gg = t >> 3, q = t & 7;
        out[node0 + t] = part[2 * gg][q] + part[2 * gg + 1][q] + bout[0];
    }
}

// ============================ launch ============================

extern "C" void kernel_launch(void* const* d_in, const int* in_sizes, int n_in,
                              void* d_out, int out_size, void* d_ws, size_t ws_size,
                              hipStream_t stream) {
    const float* x    = (const float*)d_in[0];
    const int*   eidx = (const int*)d_in[1];
    const int*   src  = eidx;
    const int*   dst  = eidx + NE;
    const float* Wl1  = (const float*)d_in[2];
    const float* Wr1  = (const float*)d_in[3];
    const float* b1   = (const float*)d_in[4];
    const float* Wl2  = (const float*)d_in[5];
    const float* Wr2  = (const float*)d_in[6];
    const float* b2   = (const float*)d_in[7];
    const float* Wout = (const float*)d_in[8];
    const float* bout = (const float*)d_in[9];

    float* out = (float*)d_out;
    float* h1f = out + NN;
    float* h2f = h1f + (size_t)NN * HID;

    // ---- workspace layout ----
    char* p = (char*)d_ws;
    int* cnt   = (int*)p;                 p += (size_t)NN * 4;
    int* off   = (int*)p;                 p += (size_t)NN * 4;
    int* cur   = (int*)p;                 p += (size_t)NN * 4;        // fallback only
    int* bsums = (int*)p;                 p += 512;                   // fallback only
    int* srcs  = (int*)p;                 p += (size_t)NE * 4;        // 6.4MB
    unsigned short* xb  = (unsigned short*)p;  p += (size_t)NN * IND * 2;   // 12.8MB
    unsigned short* m1b = (unsigned short*)p;  p += (size_t)NN * IND * 2;   // 12.8MB
    unsigned short* h1b = (unsigned short*)p;  p += (size_t)NN * HID * 2;   // 25.6MB
    unsigned short* m2b = (unsigned short*)p;  p += (size_t)NN * HID * 2;   // 25.6MB
    unsigned short* Wp1 = (unsigned short*)p;  p += 8 * 4 * 64 * 8 * 2;     // 32KB
    unsigned short* Wp2 = (unsigned short*)p;  p += 8 * 8 * 64 * 8 * 2;     // 64KB
    const size_t need_full = (size_t)(p - (char*)d_ws);
    // v2 binning extras
    int* bcnt   = (int*)p;                p += 256 * 4;
    int* bbase  = (int*)p;                p += 256 * 4;
    int* bktcur = (int*)p;                p += 256 * 4;
    unsigned* bsrc = (unsigned*)p;        p += (size_t)NE * 4;        // 6.4MB
    const size_t need_v2  = (size_t)(p - (char*)d_ws);
    const size_t need_csr = ((size_t)3 * NN + 128 + NE) * sizeof(int);

    if (ws_size >= need_v2) {
        // --- CSR build v2: two-level binning ---
        zero_small_kernel<<<1, 256, 0, stream>>>(bcnt, NBKT);
        bucket_hist_kernel<<<NBLK_E, 512, 0, stream>>>(dst, bcnt);
        bucket_scan_kernel<<<1, 64, 0, stream>>>(bcnt, bbase, bktcur);
        binA_kernel<<<NBLK_E, 512, 0, stream>>>(src, dst, bktcur, bsrc);
        binB_kernel<<<NBKT, 512, 0, stream>>>(bsrc, bbase, cnt, off, srcs);
        // --- bf16 conversions / weight packing ---
        cvt_x_kernel<<<(NN * IND / 4) / 256, 256, 0, stream>>>((const float4*)x, (ushort4*)xb);
        packW_kernel<<<8, 256, 0, stream>>>(Wr1, Wl1, IND, 4, Wp1);
        packW_kernel<<<16, 256, 0, stream>>>(Wr2, Wl2, HID, 8, Wp2);
        // --- layer 1 ---
        agg1_kernel<<<NN / 4, 256, 0, stream>>>(xb, srcs, off, cnt, m1b);
        mfma1_kernel<<<(NN + 63) / 64, 256, 0, stream>>>(xb, m1b, Wp1, b1, h1f, h1b);
        // --- layer 2 + head ---
        agg2_kernel<<<NN / 4, 256, 0, stream>>>(h1b, srcs, off, cnt, m2b);
        mfma2_kernel<<<(NN + 63) / 64, 256, 0, stream>>>(h1b, m2b, Wp2, b2, Wout, bout, h2f, out);
    } else if (ws_size >= need_full) {
        // --- round-3 path (atomic CSR fill) ---
        zero_int_kernel<<<(NN / 4 + 255) / 256, 256, 0, stream>>>((int4*)cnt, NN / 4);
        hist_kernel<<<(NE + 255) / 256, 256, 0, stream>>>(dst, cnt);
        scanA_kernel<<<NSB, 256, 0, stream>>>(cnt, bsums);
        scanB_kernel<<<1, 1, 0, stream>>>(bsums);
        scanC_kernel<<<NSB, 256, 0, stream>>>(cnt, bsums, off, cur);
        fill_kernel<<<(NE + 255) / 256, 256, 0, stream>>>(src, dst, cur, srcs);
        cvt_x_kernel<<<(NN * IND / 4) / 256, 256, 0, stream>>>((const float4*)x, (ushort4*)xb);
        packW_kernel<<<8, 256, 0, stream>>>(Wr1, Wl1, IND, 4, Wp1);
        packW_kernel<<<16, 256, 0, stream>>>(Wr2, Wl2, HID, 8, Wp2);
        agg1_kernel<<<NN / 4, 256, 0, stream>>>(xb, srcs, off, cnt, m1b);
        mfma1_kernel<<<(NN + 63) / 64, 256, 0, stream>>>(xb, m1b, Wp1, b1, h1f, h1b);
        agg2_kernel<<<NN / 4, 256, 0, stream>>>(h1b, srcs, off, cnt, m2b);
        mfma2_kernel<<<(NN + 63) / 64, 256, 0, stream>>>(h1b, m2b, Wp2, b2, Wout, bout, h2f, out);
    } else if (ws_size >= need_csr) {
        // --- round-2 fp32 path ---
        zero_int_kernel<<<(NN / 4 + 255) / 256, 256, 0, stream>>>((int4*)cnt, NN / 4);
        hist_kernel<<<(NE + 255) / 256, 256, 0, stream>>>(dst, cnt);
        scanA_kernel<<<NSB, 256, 0, stream>>>(cnt, bsums);
        scanB_kernel<<<1, 1, 0, stream>>>(bsums);
        scanC_kernel<<<NSB, 256, 0, stream>>>(cnt, bsums, off, cur);
        fill_kernel<<<(NE + 255) / 256, 256, 0, stream>>>(src, dst, cur, srcs);
        agg1f_kernel<<<NN / 4, 256, 0, stream>>>(x, srcs, off, cnt, h1f);
        gemm1f_kernel<<<NN / 16, 256, 0, stream>>>(x, Wl1, Wr1, b1, h1f);
        agg2f_kernel<<<NN / 2, 256, 0, stream>>>(h1f, srcs, off, cnt, h2f);
        gemm2f_kernel<<<NN / 16, 256, 0, stream>>>(h1f, Wl2, Wr2, b2, Wout, bout, h2f, out);
    }
}

// Round 5
// 225.414 us; speedup vs baseline: 20.5567x; 1.1496x over previous
//
#include <hip/hip_runtime.h>

#define NN 100000
#define IND 64
#define HID 128
#define NE 1600000

// ---- CSR build v3: fixed-capacity 256-node buckets ----
#define BKT2 256
#define NBKT2 ((NN + BKT2 - 1) / BKT2)     // 391 buckets
#define CAP 4992                           // mean 4092 + ~14 sigma
#define EPB 4096
#define NBLK_E ((NE + EPB - 1) / EPB)      // 391 edge chunks

// ---- fallback fp32 CSR path ----
#define SCAN_CHUNK 1024
#define NSB ((NN + SCAN_CHUNK - 1) / SCAN_CHUNK)

typedef __attribute__((ext_vector_type(8))) short bf16x8;
typedef __attribute__((ext_vector_type(4))) float f32x4;
typedef __attribute__((ext_vector_type(2))) float f32x2;

static __device__ __forceinline__ unsigned short f2bf(float f) {
    unsigned u = __float_as_uint(f);
    u = (u + 0x7FFFu + ((u >> 16) & 1u)) >> 16;   // RNE
    return (unsigned short)u;
}
static __device__ __forceinline__ unsigned pack2(float a, float b) {
    return (unsigned)f2bf(a) | ((unsigned)f2bf(b) << 16);
}

// ===================== CSR build v3 =====================

__global__ __launch_bounds__(512) void zero_small_kernel(int* __restrict__ p, int n) {
    int i = threadIdx.x;
    if (i < n) p[i] = 0;
}

// bin edges into fixed-capacity bucket regions as packed (dstlow<<17 | src)
__global__ __launch_bounds__(512) void binA_kernel(const int* __restrict__ src,
                                                   const int* __restrict__ dst,
                                                   int* __restrict__ bktcur,
                                                   unsigned* __restrict__ bins) {
    __shared__ int hcnt[NBKT2];
    __shared__ int rbase[NBKT2];
    int t = threadIdx.x;
    int e0 = blockIdx.x * EPB;
    int ce = min(EPB, NE - e0);
    for (int i = t; i < NBKT2; i += 512) hcnt[i] = 0;
    __syncthreads();
    for (int i = t; i < ce; i += 512)
        atomicAdd(&hcnt[dst[e0 + i] >> 8], 1);
    __syncthreads();
    for (int i = t; i < NBKT2; i += 512) {
        int c = hcnt[i];
        rbase[i] = c ? atomicAdd(&bktcur[i], c) : 0;
        hcnt[i] = 0;
    }
    __syncthreads();
    for (int i = t; i < ce; i += 512) {
        int d = dst[e0 + i];
        int b = d >> 8;
        int r = atomicAdd(&hcnt[b], 1);
        bins[(size_t)b * CAP + rbase[b] + r] =
            (unsigned)src[e0 + i] | ((unsigned)(d & 255) << 17);
    }
}

// per-bucket: LDS-staged exact CSR (in-place permute of bins -> srcs) + cnt/off
__global__ __launch_bounds__(256) void binB_kernel(const int* __restrict__ bktcur,
                                                   unsigned* __restrict__ bins,
                                                   int* __restrict__ cnt,
                                                   int* __restrict__ off) {
    __shared__ unsigned ebuf[CAP];
    __shared__ int ncnt[BKT2];
    __shared__ int nofs[BKT2];
    __shared__ int wtot[4];
    int t = threadIdx.x, lane = t & 63, w = t >> 6;
    int b = blockIdx.x;
    int m = bktcur[b];
    size_t base = (size_t)b * CAP;
    for (int i = t; i < m; i += 256) ebuf[i] = bins[base + i];
    ncnt[t] = 0;
    __syncthreads();
    for (int i = t; i < m; i += 256)
        atomicAdd(&ncnt[ebuf[i] >> 17], 1);
    __syncthreads();
    int v = ncnt[t];
    int incl = v;
    #pragma unroll
    for (int o = 1; o < 64; o <<= 1) {
        int u = __shfl_up(incl, o);
        if (lane >= o) incl += u;
    }
    if (lane == 63) wtot[w] = incl;
    __syncthreads();
    int wbase = 0;
    #pragma unroll
    for (int i = 0; i < 4; ++i) if (i < w) wbase += wtot[i];
    int ex = wbase + incl - v;
    nofs[t] = ex;
    int node = b * BKT2 + t;
    if (node < NN) { cnt[node] = v; off[node] = (int)base + ex; }
    __syncthreads();
    for (int i = t; i < m; i += 256) {
        unsigned val = ebuf[i];
        int r = atomicAdd(&nofs[val >> 17], 1);
        bins[base + r] = val & 0x1FFFFu;
    }
}

// ===================== conversions / packing =====================

__global__ __launch_bounds__(256) void cvt_xq_kernel(const float4* __restrict__ x,
                                                     unsigned* __restrict__ xq) {
    int i = blockIdx.x * 256 + threadIdx.x;   // over NN*IND/4 exact
    float4 v = x[i];
    int u = __builtin_amdgcn_cvt_pk_fp8_f32(v.x, v.y, 0, false);
    u = __builtin_amdgcn_cvt_pk_fp8_f32(v.z, v.w, u, true);
    xq[i] = (unsigned)u;
}

// pack Wcat = [Wr(k<Khalf) ; Wl] into MFMA B-fragment order
__global__ __launch_bounds__(256) void packW_kernel(const float* __restrict__ Wr,
                                                    const float* __restrict__ Wl,
                                                    int Khalf, int KS,
                                                    unsigned short* __restrict__ Wp) {
    int t = blockIdx.x * 256 + threadIdx.x;
    if (t >= 8 * KS * 64) return;
    int l  = t & 63;
    int ks = (t >> 6) % KS;
    int jt = t / (64 * KS);
    int j  = jt * 16 + (l & 15);
    int kb = ks * 32 + (l >> 4) * 8;
    unsigned short v[8];
    #pragma unroll
    for (int i = 0; i < 8; ++i) {
        int k = kb + i;
        float w = (k < Khalf) ? Wr[k * HID + j] : Wl[(k - Khalf) * HID + j];
        v[i] = f2bf(w);
    }
    ushort4 lo, hi;
    lo.x = v[0]; lo.y = v[1]; lo.z = v[2]; lo.w = v[3];
    hi.x = v[4]; hi.y = v[5]; hi.z = v[6]; hi.w = v[7];
    ushort4* d = reinterpret_cast<ushort4*>(Wp + (size_t)t * 8);
    d[0] = lo; d[1] = hi;
}

// ===================== fp8 gather means =====================

// 64 dims; 16 lanes/row (4 dims/lane), 4-edge parallel per wave, 4 nodes/block
__global__ __launch_bounds__(256) void agg1_kernel(const unsigned char* __restrict__ xq,
                                                   const int* __restrict__ srcs,
                                                   const int* __restrict__ off,
                                                   const int* __restrict__ cnt,
                                                   unsigned short* __restrict__ m1b) {
    int t = threadIdx.x;
    int n = blockIdx.x * 4 + (t >> 6);
    int l = t & 63, ep = l >> 4, d4 = (l & 15) * 4;
    int s0 = off[n], deg = cnt[n];
    float a0 = 0.f, a1 = 0.f, a2 = 0.f, a3 = 0.f;
    int e = ep;
    for (; e + 4 < deg; e += 8) {
        int sA = srcs[s0 + e], sB = srcs[s0 + e + 4];
        unsigned uA = *reinterpret_cast<const unsigned*>(xq + (size_t)sA * IND + d4);
        unsigned uB = *reinterpret_cast<const unsigned*>(xq + (size_t)sB * IND + d4);
        f32x2 lA = __builtin_amdgcn_cvt_pk_f32_fp8((int)uA, false);
        f32x2 hA = __builtin_amdgcn_cvt_pk_f32_fp8((int)uA, true);
        f32x2 lB = __builtin_amdgcn_cvt_pk_f32_fp8((int)uB, false);
        f32x2 hB = __builtin_amdgcn_cvt_pk_f32_fp8((int)uB, true);
        a0 += lA.x + lB.x; a1 += lA.y + lB.y;
        a2 += hA.x + hB.x; a3 += hA.y + hB.y;
    }
    for (; e < deg; e += 4) {
        int s = srcs[s0 + e];
        unsigned u = *reinterpret_cast<const unsigned*>(xq + (size_t)s * IND + d4);
        f32x2 lo = __builtin_amdgcn_cvt_pk_f32_fp8((int)u, false);
        f32x2 hi = __builtin_amdgcn_cvt_pk_f32_fp8((int)u, true);
        a0 += lo.x; a1 += lo.y; a2 += hi.x; a3 += hi.y;
    }
    a0 += __shfl_down(a0, 32); a1 += __shfl_down(a1, 32);
    a2 += __shfl_down(a2, 32); a3 += __shfl_down(a3, 32);
    a0 += __shfl_down(a0, 16); a1 += __shfl_down(a1, 16);
    a2 += __shfl_down(a2, 16); a3 += __shfl_down(a3, 16);
    if (l < 16) {
        float inv = 1.f / fmaxf((float)deg, 1.f);
        uint2 o;
        o.x = pack2(a0 * inv, a1 * inv);
        o.y = pack2(a2 * inv, a3 * inv);
        *reinterpret_cast<uint2*>(m1b + (size_t)n * IND + d4) = o;
    }
}

// 128 dims; 32 lanes/row (4 dims/lane), 2-edge parallel per wave, 4 nodes/block
__global__ __launch_bounds__(256) void agg2_kernel(const unsigned char* __restrict__ h1q,
                                                   const int* __restrict__ srcs,
                                                   const int* __restrict__ off,
                                                   const int* __restrict__ cnt,
                                                   unsigned short* __restrict__ m2b) {
    int t = threadIdx.x;
    int n = blockIdx.x * 4 + (t >> 6);
    int l = t & 63, ep = l >> 5, d4 = (l & 31) * 4;
    int s0 = off[n], deg = cnt[n];
    float a0 = 0.f, a1 = 0.f, a2 = 0.f, a3 = 0.f;
    int e = ep;
    for (; e + 6 < deg; e += 8) {
        int sA = srcs[s0 + e],     sB = srcs[s0 + e + 2];
        int sC = srcs[s0 + e + 4], sD = srcs[s0 + e + 6];
        unsigned uA = *reinterpret_cast<const unsigned*>(h1q + (size_t)sA * HID + d4);
        unsigned uB = *reinterpret_cast<const unsigned*>(h1q + (size_t)sB * HID + d4);
        unsigned uC = *reinterpret_cast<const unsigned*>(h1q + (size_t)sC * HID + d4);
        unsigned uD = *reinterpret_cast<const unsigned*>(h1q + (size_t)sD * HID + d4);
        f32x2 lA = __builtin_amdgcn_cvt_pk_f32_fp8((int)uA, false);
        f32x2 hA = __builtin_amdgcn_cvt_pk_f32_fp8((int)uA, true);
        f32x2 lB = __builtin_amdgcn_cvt_pk_f32_fp8((int)uB, false);
        f32x2 hB = __builtin_amdgcn_cvt_pk_f32_fp8((int)uB, true);
        f32x2 lC = __builtin_amdgcn_cvt_pk_f32_fp8((int)uC, false);
        f32x2 hC = __builtin_amdgcn_cvt_pk_f32_fp8((int)uC, true);
        f32x2 lD = __builtin_amdgcn_cvt_pk_f32_fp8((int)uD, false);
        f32x2 hD = __builtin_amdgcn_cvt_pk_f32_fp8((int)uD, true);
        a0 += (lA.x + lB.x) + (lC.x + lD.x);
        a1 += (lA.y + lB.y) + (lC.y + lD.y);
        a2 += (hA.x + hB.x) + (hC.x + hD.x);
        a3 += (hA.y + hB.y) + (hC.y + hD.y);
    }
    for (; e < deg; e += 2) {
        int s = srcs[s0 + e];
        unsigned u = *reinterpret_cast<const unsigned*>(h1q + (size_t)s * HID + d4);
        f32x2 lo = __builtin_amdgcn_cvt_pk_f32_fp8((int)u, false);
        f32x2 hi = __builtin_amdgcn_cvt_pk_f32_fp8((int)u, true);
        a0 += lo.x; a1 += lo.y; a2 += hi.x; a3 += hi.y;
    }
    a0 += __shfl_down(a0, 32); a1 += __shfl_down(a1, 32);
    a2 += __shfl_down(a2, 32); a3 += __shfl_down(a3, 32);
    if (l < 32) {
        float inv = 1.f / fmaxf((float)deg, 1.f);
        uint2 o;
        o.x = pack2(a0 * inv, a1 * inv);
        o.y = pack2(a2 * inv, a3 * inv);
        *reinterpret_cast<uint2*>(m2b + (size_t)n * HID + d4) = o;
    }
}

// ===================== MFMA dense layers =====================

// layer1: h1 = relu([x | m1b] @ Wp1 + b1); reads x fp32 directly
__global__ __launch_bounds__(256) void mfma1_kernel(const float* __restrict__ x,
                                                    const unsigned short* __restrict__ m1b,
                                                    const unsigned short* __restrict__ Wp,
                                                    const float* __restrict__ b,
                                                    float* __restrict__ h1f,
                                                    unsigned short* __restrict__ h1b,
                                                    unsigned char* __restrict__ h1q) {
    int t = threadIdx.x, w = t >> 6, l = t & 63;
    int row0 = blockIdx.x * 64 + w * 16;
    int arow = row0 + (l & 15); if (arow > NN - 1) arow = NN - 1;
    int kcol = (l >> 4) * 8;
    f32x4 acc[8];
    #pragma unroll
    for (int jt = 0; jt < 8; ++jt) { acc[jt][0] = 0.f; acc[jt][1] = 0.f; acc[jt][2] = 0.f; acc[jt][3] = 0.f; }
    #pragma unroll
    for (int ks = 0; ks < 4; ++ks) {
        bf16x8 a;
        int c = (ks & 1) * 32 + kcol;
        if (ks < 2) {
            const float* xr = x + (size_t)arow * IND + c;
            float4 f0 = *reinterpret_cast<const float4*>(xr);
            float4 f1 = *reinterpret_cast<const float4*>(xr + 4);
            a[0] = (short)f2bf(f0.x); a[1] = (short)f2bf(f0.y);
            a[2] = (short)f2bf(f0.z); a[3] = (short)f2bf(f0.w);
            a[4] = (short)f2bf(f1.x); a[5] = (short)f2bf(f1.y);
            a[6] = (short)f2bf(f1.z); a[7] = (short)f2bf(f1.w);
        } else {
            a = *reinterpret_cast<const bf16x8*>(m1b + (size_t)arow * IND + c);
        }
        #pragma unroll
        for (int jt = 0; jt < 8; ++jt) {
            bf16x8 bb = *reinterpret_cast<const bf16x8*>(Wp + ((size_t)(jt * 4 + ks) * 64 + l) * 8);
            acc[jt] = __builtin_amdgcn_mfma_f32_16x16x32_bf16(a, bb, acc[jt], 0, 0, 0);
        }
    }
    int rbase = row0 + (l >> 4) * 4;
    #pragma unroll
    for (int jt = 0; jt < 8; ++jt) {
        int col = jt * 16 + (l & 15);
        float bias = b[col];
        #pragma unroll
        for (int r = 0; r < 4; ++r) {
            int row = rbase + r;
            if (row < NN) {
                float v = fmaxf(acc[jt][r] + bias, 0.f);
                h1f[(size_t)row * HID + col] = v;
                h1b[(size_t)row * HID + col] = f2bf(v);
                unsigned q8 = (unsigned)__builtin_amdgcn_cvt_pk_fp8_f32(v, 0.f, 0, false) & 0xFFu;
                h1q[(size_t)row * HID + col] = (unsigned char)q8;
            }
        }
    }
}

// layer2 + head: h2 = [h1b | m2b] @ Wp2 + b2; out = h2 @ Wout + bout
__global__ __launch_bounds__(256) void mfma2_kernel(const unsigned short* __restrict__ h1b,
                                                    const unsigned short* __restrict__ m2b,
                                                    const unsigned short* __restrict__ Wp,
                                                    const float* __restrict__ b,
                                                    const float* __restrict__ Wout,
                                                    const float* __restrict__ bout,
                                                    float* __restrict__ h2f,
                                                    float* __restrict__ out) {
    int t = threadIdx.x, w = t >> 6, l = t & 63;
    int row0 = blockIdx.x * 64 + w * 16;
    int arow = row0 + (l & 15); if (arow > NN - 1) arow = NN - 1;
    int kcol = (l >> 4) * 8;
    f32x4 acc[8];
    #pragma unroll
    for (int jt = 0; jt < 8; ++jt) { acc[jt][0] = 0.f; acc[jt][1] = 0.f; acc[jt][2] = 0.f; acc[jt][3] = 0.f; }
    #pragma unroll
    for (int ks = 0; ks < 8; ++ks) {
        const unsigned short* A = (ks < 4) ? h1b : m2b;
        int c = (ks & 3) * 32 + kcol;
        bf16x8 a = *reinterpret_cast<const bf16x8*>(A + (size_t)arow * HID + c);
        #pragma unroll
        for (int jt = 0; jt < 8; ++jt) {
            bf16x8 bb = *reinterpret_cast<const bf16x8*>(Wp + ((size_t)(jt * 8 + ks) * 64 + l) * 8);
            acc[jt] = __builtin_amdgcn_mfma_f32_16x16x32_bf16(a, bb, acc[jt], 0, 0, 0);
        }
    }
    int rbase = row0 + (l >> 4) * 4;
    float hs0 = 0.f, hs1 = 0.f, hs2 = 0.f, hs3 = 0.f;
    #pragma unroll
    for (int jt = 0; jt < 8; ++jt) {
        int col = jt * 16 + (l & 15);
        float bias = b[col];
        float wo = Wout[col];
        #pragma unroll
        for (int r = 0; r < 4; ++r) {
            int row = rbase + r;
            float v = acc[jt][r] + bias;
            if (row < NN) h2f[(size_t)row * HID + col] = v;
            if (r == 0) hs0 += v * wo;
            else if (r == 1) hs1 += v * wo;
            else if (r == 2) hs2 += v * wo;
            else hs3 += v * wo;
        }
    }
    #pragma unroll
    for (int o = 1; o < 16; o <<= 1) {
        hs0 += __shfl_xor(hs0, o);
        hs1 += __shfl_xor(hs1, o);
        hs2 += __shfl_xor(hs2, o);
        hs3 += __shfl_xor(hs3, o);
    }
    if ((l & 15) == 0) {
        float bo = bout[0];
        if (rbase + 0 < NN) out[rbase + 0] = hs0 + bo;
        if (rbase + 1 < NN) out[rbase + 1] = hs1 + bo;
        if (rbase + 2 < NN) out[rbase + 2] = hs2 + bo;
        if (rbase + 3 < NN) out[rbase + 3] = hs3 + bo;
    }
}

// ===================== fp32 CSR fallback (round-2) =====================

__global__ __launch_bounds__(256) void zero_int_kernel(int4* __restrict__ p, int n4) {
    int i = blockIdx.x * 256 + threadIdx.x;
    if (i < n4) p[i] = make_int4(0, 0, 0, 0);
}

__global__ __launch_bounds__(256) void hist_kernel(const int* __restrict__ dst,
                                                   int* __restrict__ cnt) {
    int e = blockIdx.x * 256 + threadIdx.x;
    if (e < NE) atomicAdd(&cnt[dst[e]], 1);
}

__global__ __launch_bounds__(256) void scanA_kernel(const int* __restrict__ cnt,
                                                    int* __restrict__ bsums) {
    int b = blockIdx.x, t = threadIdx.x;
    int base = b * SCAN_CHUNK + t * 4;
    int s = 0;
    #pragma unroll
    for (int k = 0; k < 4; ++k) { int i = base + k; if (i < NN) s += cnt[i]; }
    #pragma unroll
    for (int o = 32; o > 0; o >>= 1) s += __shfl_down(s, o);
    __shared__ int wsum[4];
    if ((t & 63) == 0) wsum[t >> 6] = s;
    __syncthreads();
    if (t == 0) bsums[b] = wsum[0] + wsum[1] + wsum[2] + wsum[3];
}

__global__ void scanB_kernel(int* __restrict__ bsums) {
    int acc = 0;
    for (int i = 0; i < NSB; ++i) { int v = bsums[i]; bsums[i] = acc; acc += v; }
}

__global__ __launch_bounds__(256) void scanC_kernel(const int* __restrict__ cnt,
                                                    const int* __restrict__ bsums,
                                                    int* __restrict__ off,
                                                    int* __restrict__ cur) {
    int b = blockIdx.x, t = threadIdx.x;
    int lane = t & 63, w = t >> 6;
    int base = b * SCAN_CHUNK + t * 4;
    int v[4]; int s = 0;
    #pragma unroll
    for (int k = 0; k < 4; ++k) {
        int i = base + k;
        v[k] = (i < NN) ? cnt[i] : 0;
        s += v[k];
    }
    int inc = s;
    #pragma unroll
    for (int o = 1; o < 64; o <<= 1) {
        int xv = __shfl_up(inc, o);
        if (lane >= o) inc += xv;
    }
    __shared__ int wsum[4];
    if (lane == 63) wsum[w] = inc;
    __syncthreads();
    int wbase = 0;
    for (int i = 0; i < w; ++i) wbase += wsum[i];
    int ex = bsums[b] + wbase + (inc - s);
    #pragma unroll
    for (int k = 0; k < 4; ++k) {
        int i = base + k;
        if (i < NN) { off[i] = ex; cur[i] = ex; }
        ex += v[k];
    }
}

__global__ __launch_bounds__(256) void fill_kernel(const int* __restrict__ src,
                                                   const int* __restrict__ dst,
                                                   int* __restrict__ cur,
                                                   int* __restrict__ srcs) {
    int e = blockIdx.x * 256 + threadIdx.x;
    if (e < NE) {
        int p = atomicAdd(&cur[dst[e]], 1);
        srcs[p] = src[e];
    }
}

__global__ __launch_bounds__(256) void agg1f_kernel(const float* __restrict__ x,
                                                    const int* __restrict__ srcs,
                                                    const int* __restrict__ off,
                                                    const int* __restrict__ cnt,
                                                    float* __restrict__ mean1) {
    int t = threadIdx.x;
    int n = blockIdx.x * 4 + (t >> 6);
    int d = t & 63;
    int s0 = off[n], deg = cnt[n];
    float acc = 0.f;
    for (int e = 0; e < deg; ++e) acc += x[(size_t)srcs[s0 + e] * IND + d];
    mean1[(size_t)n * HID + d] = acc / fmaxf((float)deg, 1.f);
}

__global__ __launch_bounds__(256) void agg2f_kernel(const float* __restrict__ h1,
                                                    const int* __restrict__ srcs,
                                                    const int* __restrict__ off,
                                                    const int* __restrict__ cnt,
                                                    float* __restrict__ mean2) {
    int t = threadIdx.x;
    int n = blockIdx.x * 2 + (t >> 7);
    int d = t & 127;
    int s0 = off[n], deg = cnt[n];
    float acc = 0.f;
    for (int e = 0; e < deg; ++e) acc += h1[(size_t)srcs[s0 + e] * HID + d];
    mean2[(size_t)n * HID + d] = acc / fmaxf((float)deg, 1.f);
}

__global__ __launch_bounds__(256) void gemm1f_kernel(const float* __restrict__ x,
                                                     const float* __restrict__ Wl,
                                                     const float* __restrict__ Wr,
                                                     const float* __restrict__ b,
                                                     float* __restrict__ h1) {
    __shared__ float in[16][128];
    int t = threadIdx.x;
    int node0 = blockIdx.x * 16;
    for (int idx = t; idx < 16 * 128; idx += 256) {
        int r = idx >> 7, c = idx & 127;
        in[r][c] = (c < IND) ? x[(size_t)(node0 + r) * IND + c]
                             : h1[(size_t)(node0 + r) * HID + (c - IND)];
    }
    __syncthreads();
    int j = t & 127, g = t >> 7;
    float acc[8];
    float bj = b[j];
    #pragma unroll
    for (int q = 0; q < 8; ++q) acc[q] = bj;
    for (int k = 0; k < 128; ++k) {
        float wv = (k < IND) ? Wr[k * HID + j] : Wl[(k - IND) * HID + j];
        #pragma unroll
        for (int q = 0; q < 8; ++q) acc[q] += in[g * 8 + q][k] * wv;
    }
    #pragma unroll
    for (int q = 0; q < 8; ++q)
        h1[(size_t)(node0 + g * 8 + q) * HID + j] = fmaxf(acc[q], 0.f);
}

__global__ __launch_bounds__(256) void gemm2f_kernel(const float* __restrict__ h1,
                                                     const float* __restrict__ Wl,
                                                     const float* __restrict__ Wr,
                                                     const float* __restrict__ b,
                                                     const float* __restrict__ Wout,
                                                     const float* __restrict__ bout,
                                                     float* __restrict__ h2,
                                                     float* __restrict__ out) {
    __shared__ float in[16][256];
    __shared__ float part[4][8];
    int t = threadIdx.x;
    int node0 = blockIdx.x * 16;
    for (int idx = t; idx < 16 * 256; idx += 256) {
        int r = idx >> 8, c = idx & 255;
        in[r][c] = (c < HID) ? h1[(size_t)(node0 + r) * HID + c]
                             : h2[(size_t)(node0 + r) * HID + (c - HID)];
    }
    __syncthreads();
    int j = t & 127, g = t >> 7, lane = t & 63, w = t >> 6;
    float acc[8];
    float bj = b[j];
    #pragma unroll
    for (int q = 0; q < 8; ++q) acc[q] = bj;
    for (int k = 0; k < 256; ++k) {
        float wv = (k < HID) ? Wr[k * HID + j] : Wl[(k - HID) * HID + j];
        #pragma unroll
        for (int q = 0; q < 8; ++q) acc[q] += in[g * 8 + q][k] * wv;
    }
    float wo = Wout[j];
    #pragma unroll
    for (int q = 0; q < 8; ++q)
        h2[(size_t)(node0 + g * 8 + q) * HID + j] = acc[q];
    #pragma unroll
    for (int q = 0; q < 8; ++q) {
        float v = acc[q] * wo;
        #pragma unroll
        for (int o = 32; o > 0; o >>= 1) v += __shfl_down(v, o);
        if (lane == 0) part[w][q] = v;
    }
    __syncthreads();
    if (t < 16) {
        int gg = t >> 3, q = t & 7;
        out[node0 + t] = part[2 * gg][q] + part[2 * gg + 1][q] + bout[0];
    }
}

// ============================ launch ============================

extern "C" void kernel_launch(void* const* d_in, const int* in_sizes, int n_in,
                              void* d_out, int out_size, void* d_ws, size_t ws_size,
                              hipStream_t stream) {
    const float* x    = (const float*)d_in[0];
    const int*   eidx = (const int*)d_in[1];
    const int*   src  = eidx;
    const int*   dst  = eidx + NE;
    const float* Wl1  = (const float*)d_in[2];
    const float* Wr1  = (const float*)d_in[3];
    const float* b1   = (const float*)d_in[4];
    const float* Wl2  = (const float*)d_in[5];
    const float* Wr2  = (const float*)d_in[6];
    const float* b2   = (const float*)d_in[7];
    const float* Wout = (const float*)d_in[8];
    const float* bout = (const float*)d_in[9];

    float* out = (float*)d_out;
    float* h1f = out + NN;
    float* h2f = h1f + (size_t)NN * HID;

    // ---- v3 workspace layout (~92 MB) ----
    char* p = (char*)d_ws;
    int* cnt        = (int*)p;            p += (size_t)NN * 4;          // 400000
    int* off        = (int*)p;            p += (size_t)NN * 4;          // 400000
    int* bktcur     = (int*)p;            p += 512 * 4;
    unsigned* bins  = (unsigned*)p;       p += (size_t)NBKT2 * CAP * 4; // 7.8MB (becomes srcs)
    unsigned char* xq  = (unsigned char*)p;  p += (size_t)NN * IND;     // 6.4MB
    unsigned short* m1b = (unsigned short*)p; p += (size_t)NN * IND * 2; // 12.8MB
    unsigned short* h1b = (unsigned short*)p; p += (size_t)NN * HID * 2; // 25.6MB
    unsigned char* h1q  = (unsigned char*)p;  p += (size_t)NN * HID;     // 12.8MB
    unsigned short* m2b = (unsigned short*)p; p += (size_t)NN * HID * 2; // 25.6MB
    unsigned short* Wp1 = (unsigned short*)p; p += 8 * 4 * 64 * 8 * 2;   // 32KB
    unsigned short* Wp2 = (unsigned short*)p; p += 8 * 8 * 64 * 8 * 2;   // 64KB
    const size_t need_v3 = (size_t)(p - (char*)d_ws);
    const size_t need_csr = ((size_t)3 * NN + 128 + NE) * sizeof(int);

    if (ws_size >= need_v3) {
        // CSR build v3 (fixed-capacity buckets, in-place permute)
        zero_small_kernel<<<1, 512, 0, stream>>>(bktcur, NBKT2);
        binA_kernel<<<NBLK_E, 512, 0, stream>>>(src, dst, bktcur, bins);
        binB_kernel<<<NBKT2, 256, 0, stream>>>(bktcur, bins, cnt, off);
        // conversions / weight packing
        cvt_xq_kernel<<<(NN * IND / 4) / 256, 256, 0, stream>>>((const float4*)x, (unsigned*)xq);
        packW_kernel<<<8, 256, 0, stream>>>(Wr1, Wl1, IND, 4, Wp1);
        packW_kernel<<<16, 256, 0, stream>>>(Wr2, Wl2, HID, 8, Wp2);
        // layer 1
        agg1_kernel<<<NN / 4, 256, 0, stream>>>(xq, (const int*)bins, off, cnt, m1b);
        mfma1_kernel<<<(NN + 63) / 64, 256, 0, stream>>>(x, m1b, Wp1, b1, h1f, h1b, h1q);
        // layer 2 + head
        agg2_kernel<<<NN / 4, 256, 0, stream>>>(h1q, (const int*)bins, off, cnt, m2b);
        mfma2_kernel<<<(NN + 63) / 64, 256, 0, stream>>>(h1b, m2b, Wp2, b2, Wout, bout, h2f, out);
    } else if (ws_size >= need_csr) {
        // fp32 CSR fallback
        int* cntF   = (int*)d_ws;
        int* offF   = cntF + NN;
        int* curF   = offF + NN;
        int* bsums  = curF + NN;
        int* srcsF  = bsums + 128;
        zero_int_kernel<<<(NN / 4 + 255) / 256, 256, 0, stream>>>((int4*)cntF, NN / 4);
        hist_kernel<<<(NE + 255) / 256, 256, 0, stream>>>(dst, cntF);
        scanA_kernel<<<NSB, 256, 0, stream>>>(cntF, bsums);
        scanB_kernel<<<1, 1, 0, stream>>>(bsums);
        scanC_kernel<<<NSB, 256, 0, stream>>>(cntF, bsums, offF, curF);
        fill_kernel<<<(NE + 255) / 256, 256, 0, stream>>>(src, dst, curF, srcsF);
        agg1f_kernel<<<NN / 4, 256, 0, stream>>>(x, srcsF, offF, cntF, h1f);
        gemm1f_kernel<<<NN / 16, 256, 0, stream>>>(x, Wl1, Wr1, b1, h1f);
        agg2f_kernel<<<NN / 2, 256, 0, stream>>>(h1f, srcsF, offF, cntF, h2f);
        gemm2f_kernel<<<NN / 16, 256, 0, stream>>>(h1f, Wl2, Wr2, b2, Wout, bout, h2f, out);
    }
}